// Round 17
// baseline (337.906 us; speedup 1.0000x reference)
//
#include <hip/hip_runtime.h>
#include <hip/hip_bf16.h>
#include <math.h>

#define BB 2
#define LL 4096
#define DD 1024
#define HH 16
#define HDIM 64
#define CC 64
#define NC 64   // LL/CC
#define BH 32   // BB*HH
#define GG 8    // chunk groups
#define GS 8    // chunks per group

typedef __attribute__((ext_vector_type(8))) short short8;
typedef __attribute__((ext_vector_type(4))) float f32x4;
typedef unsigned short u16;
typedef unsigned int u32;

__device__ __forceinline__ u16 f2bf(float f) {
    unsigned int u = __float_as_uint(f);
    unsigned int r = (u + 0x7fffu + ((u >> 16) & 1u)) >> 16;
    return (u16)r;
}
__device__ __forceinline__ float bf2f(u16 h) {
    return __uint_as_float((unsigned)h << 16);
}
__device__ __forceinline__ void split2(float x, u16& h, u16& l) {
    h = f2bf(x);
    l = f2bf(x - bf2f(h));
}
__device__ __forceinline__ float4 ld_bf4(const u16* p) {
    uint2 v = *(const uint2*)p;
    return make_float4(bf2f((u16)v.x), bf2f((u16)(v.x >> 16)),
                       bf2f((u16)v.y), bf2f((u16)(v.y >> 16)));
}

__device__ __forceinline__ void gld_lds16(const void* g, void* l) {
    __builtin_amdgcn_global_load_lds(
        (const __attribute__((address_space(1))) void*)g,
        (__attribute__((address_space(3))) void*)l, 16, 0, 0);
}

// fp32 [64][64] tile swizzle (4-elem chunks XOR'd by row>>2)
__device__ __forceinline__ int swz(int r, int c) {
    return (r << 6) + ((((c >> 2) ^ (r >> 2)) & 15) << 2) + (c & 3);
}
// bf16 [64][64] tile swizzle (reads + stride-4 transposed writes both 2-way)
__device__ __forceinline__ int swze(int r, int c) {
    return (r << 6) + (c ^ (((r ^ (r >> 3)) & 7) << 3));
}

// ---------------------------------------------------------------------------
// mm64 variants: C[a][b] += sum_k A[a][k]*B[b][k]; A,B in swizzled LDS tiles.
// ---------------------------------------------------------------------------
__device__ __forceinline__ void mm64(const u16* __restrict__ Ah, const u16* __restrict__ Al,
                                     const u16* __restrict__ Bh, const u16* __restrict__ Bl,
                                     f32x4* acc, int w, int lane) {
    const int ln = lane & 15, kg = (lane >> 4) * 8;
#pragma unroll
    for (int kb = 0; kb < 2; ++kb) {
        const int k0 = kb * 32 + kg;
        short8 ah = *(const short8*)&Ah[swze(w * 16 + ln, k0)];
        short8 al = *(const short8*)&Al[swze(w * 16 + ln, k0)];
#pragma unroll
        for (int j = 0; j < 4; ++j) {
            short8 bh = *(const short8*)&Bh[swze(j * 16 + ln, k0)];
            short8 bl = *(const short8*)&Bl[swze(j * 16 + ln, k0)];
            acc[j] = __builtin_amdgcn_mfma_f32_16x16x32_bf16(ah, bh, acc[j], 0, 0, 0);
            acc[j] = __builtin_amdgcn_mfma_f32_16x16x32_bf16(ah, bl, acc[j], 0, 0, 0);
            acc[j] = __builtin_amdgcn_mfma_f32_16x16x32_bf16(al, bh, acc[j], 0, 0, 0);
        }
    }
}
// both operands exact bf16
__device__ __forceinline__ void mm64_bb(const u16* __restrict__ Ah,
                                        const u16* __restrict__ Bh,
                                        f32x4* acc, int w, int lane) {
    const int ln = lane & 15, kg = (lane >> 4) * 8;
#pragma unroll
    for (int kb = 0; kb < 2; ++kb) {
        const int k0 = kb * 32 + kg;
        short8 ah = *(const short8*)&Ah[swze(w * 16 + ln, k0)];
#pragma unroll
        for (int j = 0; j < 4; ++j) {
            short8 bh = *(const short8*)&Bh[swze(j * 16 + ln, k0)];
            acc[j] = __builtin_amdgcn_mfma_f32_16x16x32_bf16(ah, bh, acc[j], 0, 0, 0);
        }
    }
}
// A exact bf16, B split
__device__ __forceinline__ void mm64_ab(const u16* __restrict__ Ah,
                                        const u16* __restrict__ Bh, const u16* __restrict__ Bl,
                                        f32x4* acc, int w, int lane) {
    const int ln = lane & 15, kg = (lane >> 4) * 8;
#pragma unroll
    for (int kb = 0; kb < 2; ++kb) {
        const int k0 = kb * 32 + kg;
        short8 ah = *(const short8*)&Ah[swze(w * 16 + ln, k0)];
#pragma unroll
        for (int j = 0; j < 4; ++j) {
            short8 bh = *(const short8*)&Bh[swze(j * 16 + ln, k0)];
            short8 bl = *(const short8*)&Bl[swze(j * 16 + ln, k0)];
            acc[j] = __builtin_amdgcn_mfma_f32_16x16x32_bf16(ah, bh, acc[j], 0, 0, 0);
            acc[j] = __builtin_amdgcn_mfma_f32_16x16x32_bf16(ah, bl, acc[j], 0, 0, 0);
        }
    }
}
// A split, B exact bf16
__device__ __forceinline__ void mm64_sb(const u16* __restrict__ Ah, const u16* __restrict__ Al,
                                        const u16* __restrict__ Bh,
                                        f32x4* acc, int w, int lane) {
    const int ln = lane & 15, kg = (lane >> 4) * 8;
#pragma unroll
    for (int kb = 0; kb < 2; ++kb) {
        const int k0 = kb * 32 + kg;
        short8 ah = *(const short8*)&Ah[swze(w * 16 + ln, k0)];
        short8 al = *(const short8*)&Al[swze(w * 16 + ln, k0)];
#pragma unroll
        for (int j = 0; j < 4; ++j) {
            short8 bh = *(const short8*)&Bh[swze(j * 16 + ln, k0)];
            acc[j] = __builtin_amdgcn_mfma_f32_16x16x32_bf16(ah, bh, acc[j], 0, 0, 0);
            acc[j] = __builtin_amdgcn_mfma_f32_16x16x32_bf16(al, bh, acc[j], 0, 0, 0);
        }
    }
}

// global bf16 [64][64] -> swizzled LDS copy
__device__ __forceinline__ void g_to_ls_b(const u16* __restrict__ G16, u16* Ah, int tid) {
#pragma unroll
    for (int p = 0; p < 2; ++p) {
        int flat = p * 2048 + tid * 8;
        int r = flat >> 6, c = flat & 63;
        *(short8*)&Ah[swze(r, c)] = *(const short8*)&G16[flat];
    }
}

// global fp32 [64][64] -> hi/lo bf16 LDS (split at consumer)
__device__ __forceinline__ void g_to_ls(const float* __restrict__ G, u16* Ah, u16* Al, int tid) {
#pragma unroll
    for (int p = 0; p < 4; ++p) {
        int flat = p * 1024 + tid * 4;
        int r = flat >> 6, c = flat & 63;
        float4 v = *(const float4*)&G[flat];
        u16 h0, l0, h1, l1, h2, l2, h3, l3;
        split2(v.x, h0, l0); split2(v.y, h1, l1);
        split2(v.z, h2, l2); split2(v.w, h3, l3);
        int idx = swze(r, c);
        uint2 hv, lv;
        hv.x = (unsigned)h0 | ((unsigned)h1 << 16); hv.y = (unsigned)h2 | ((unsigned)h3 << 16);
        lv.x = (unsigned)l0 | ((unsigned)l1 << 16); lv.y = (unsigned)l2 | ((unsigned)l3 << 16);
        *(uint2*)&Ah[idx] = hv;
        *(uint2*)&Al[idx] = lv;
    }
}

// fp32 global: register prefetch + split LDS store (T14)
__device__ __forceinline__ void pload_f(float4 pf[4], const float* __restrict__ G, int tid) {
    pf[0] = *(const float4*)&G[tid * 8];
    pf[1] = *(const float4*)&G[tid * 8 + 4];
    pf[2] = *(const float4*)&G[2048 + tid * 8];
    pf[3] = *(const float4*)&G[2048 + tid * 8 + 4];
}
__device__ __forceinline__ void pstore_ls_f(const float4 pf[4], u16* Ah, u16* Al, int tid) {
#pragma unroll
    for (int p = 0; p < 2; ++p) {
        int flat = p * 2048 + tid * 8;
        int r = flat >> 6, c = flat & 63;
        float4 a = pf[2 * p], b = pf[2 * p + 1];
        u16 h[8], l[8];
        split2(a.x, h[0], l[0]); split2(a.y, h[1], l[1]);
        split2(a.z, h[2], l[2]); split2(a.w, h[3], l[3]);
        split2(b.x, h[4], l[4]); split2(b.y, h[5], l[5]);
        split2(b.z, h[6], l[6]); split2(b.w, h[7], l[7]);
        short8 hi, lo;
#pragma unroll
        for (int e = 0; e < 8; ++e) { hi[e] = (short)h[e]; lo[e] = (short)l[e]; }
        *(short8*)&Ah[swze(r, c)] = hi;
        *(short8*)&Al[swze(r, c)] = lo;
    }
}

// register frag -> hi/lo bf16 LDS
__device__ __forceinline__ void frag_to_ls(const f32x4* acc, u16* Ah, u16* Al, int w, int lane) {
    const int g = lane >> 4, ln = lane & 15;
#pragma unroll
    for (int j = 0; j < 4; ++j)
#pragma unroll
        for (int r = 0; r < 4; ++r) {
            int row = w * 16 + g * 4 + r, col = j * 16 + ln;
            u16 h, l; split2(acc[j][r], h, l);
            Ah[swze(row, col)] = h;
            Al[swze(row, col)] = l;
        }
}

// fp32-global frag helpers
__device__ __forceinline__ void g_to_frag(const float* __restrict__ G, f32x4* acc, int w, int lane) {
    const int g = lane >> 4, ln = lane & 15;
#pragma unroll
    for (int j = 0; j < 4; ++j)
#pragma unroll
        for (int r = 0; r < 4; ++r)
            acc[j][r] = G[(w * 16 + g * 4 + r) * 64 + j * 16 + ln];
}
__device__ __forceinline__ void g_add_frag(const float* __restrict__ G, f32x4* acc, int w, int lane) {
    const int g = lane >> 4, ln = lane & 15;
#pragma unroll
    for (int j = 0; j < 4; ++j)
#pragma unroll
        for (int r = 0; r < 4; ++r)
            acc[j][r] += G[(w * 16 + g * 4 + r) * 64 + j * 16 + ln];
}
__device__ __forceinline__ void frag_to_g(const f32x4* acc, float* __restrict__ G, int w, int lane) {
    const int g = lane >> 4, ln = lane & 15;
#pragma unroll
    for (int j = 0; j < 4; ++j)
#pragma unroll
        for (int r = 0; r < 4; ++r)
            G[(w * 16 + g * 4 + r) * 64 + j * 16 + ln] = acc[j][r];
}

// ---------------------------------------------------------------------------
// prep: fused fp32->bf16 cast of x (bid<4096) + 4x W transpose-cast (else)
// ---------------------------------------------------------------------------
__global__ __launch_bounds__(256) void prep_k(const float* __restrict__ in,
                                              u16* __restrict__ out,
                                              const float* __restrict__ W0,
                                              const float* __restrict__ W1,
                                              const float* __restrict__ W2,
                                              const float* __restrict__ W3,
                                              u16* __restrict__ WT0) {
    __shared__ float t[32][33];
    const int bid = blockIdx.x;
    if (bid < 4096) {
        int i = (bid * 256 + threadIdx.x) * 8;
        float4 a = *(const float4*)&in[i];
        float4 b = *(const float4*)&in[i + 4];
        uint4 o;
        o.x = (unsigned)f2bf(a.x) | ((unsigned)f2bf(a.y) << 16);
        o.y = (unsigned)f2bf(a.z) | ((unsigned)f2bf(a.w) << 16);
        o.z = (unsigned)f2bf(b.x) | ((unsigned)f2bf(b.y) << 16);
        o.w = (unsigned)f2bf(b.z) | ((unsigned)f2bf(b.w) << 16);
        *(uint4*)&out[i] = o;
        return;
    }
    const int t2 = bid - 4096;
    const int which = t2 >> 10, rem = t2 & 1023;
    const int bx = (rem & 31) * 32, by = (rem >> 5) * 32;
    const float* W = (which == 0) ? W0 : (which == 1) ? W1 : (which == 2) ? W2 : W3;
    u16* WT = WT0 + (size_t)which * 1048576;
#pragma unroll
    for (int p = 0; p < 4; ++p) {
        int idx = p * 256 + threadIdx.x;
        int r = idx >> 5, cc = idx & 31;
        t[r][cc] = W[(size_t)(by + r) * 1024 + bx + cc];
    }
    __syncthreads();
#pragma unroll
    for (int p = 0; p < 4; ++p) {
        int idx = p * 256 + threadIdx.x;
        int r = idx >> 5, cc = idx & 31;
        WT[(size_t)(bx + r) * 1024 + by + cc] = f2bf(t[cc][r]);
    }
}

// ---------------------------------------------------------------------------
// GEMM core (deep): 256x256 tile, 8 waves, 4 LDS bufs (128KB, 1 block/CU),
// 3-ahead prefetch, one barrier per K-step, frag ping-pong.
// ---------------------------------------------------------------------------
__device__ __forceinline__ void gemm_core256(const u16* A, const u16* BT,
                                             int m0, int n0, f32x4 acc[8][4]) {
    __shared__ __align__(16) short As[4][256 * 32];
    __shared__ __align__(16) short Bs[4][256 * 32];
    const int tid = threadIdx.x;
    const int lane = tid & 63, w = tid >> 6;
    const int wr = w >> 2, wc = w & 3;
    const int ln15 = lane & 15, kch = lane >> 4;
    const int erow = tid >> 2;
    const int ecol = (((tid & 3) ^ ((tid >> 3) & 3)) << 3);

#define STAGE256(buf, t)                                                      \
    {   const int k0_ = (t) * 32;                                             \
        _Pragma("unroll")                                                     \
        for (int rr = 0; rr < 2; ++rr) {                                      \
            gld_lds16(A  + (size_t)(m0 + rr * 128 + erow) * 1024 + k0_ + ecol,\
                      (short*)As[buf] + rr * 4096 + tid * 8);                 \
            gld_lds16(BT + (size_t)(n0 + rr * 128 + erow) * 1024 + k0_ + ecol,\
                      (short*)Bs[buf] + rr * 4096 + tid * 8);                 \
        } }

#define RF256(Fa, Fb, buf)                                                    \
    {   _Pragma("unroll")                                                     \
        for (int i = 0; i < 8; ++i) {                                         \
            int row = wr * 128 + i * 16 + ln15;                               \
            Fa[i] = *(const short8*)&As[buf][row * 32 + ((kch ^ ((row >> 1) & 3)) << 3)]; \
        }                                                                     \
        _Pragma("unroll")                                                     \
        for (int j = 0; j < 4; ++j) {                                         \
            int row = wc * 64 + j * 16 + ln15;                                \
            Fb[j] = *(const short8*)&Bs[buf][row * 32 + ((kch ^ ((row >> 1) & 3)) << 3)]; \
        } }

#define MM256(Fa, Fb)                                                         \
    {   __builtin_amdgcn_s_setprio(1);                                        \
        _Pragma("unroll")                                                     \
        for (int i = 0; i < 8; ++i)                                           \
            _Pragma("unroll")                                                 \
            for (int j = 0; j < 4; ++j)                                       \
                acc[i][j] = __builtin_amdgcn_mfma_f32_16x16x32_bf16(Fa[i], Fb[j], acc[i][j], 0, 0, 0); \
        __builtin_amdgcn_s_setprio(0); }

#define BODY256(t, Ca, Cb, Na, Nb)                                            \
    {   if ((t) + 3 < 32) STAGE256(((t) + 3) & 3, (t) + 3);                   \
        if ((t) < 29)       asm volatile("s_waitcnt vmcnt(8)" ::: "memory");  \
        else if ((t) == 29) asm volatile("s_waitcnt vmcnt(4)" ::: "memory");  \
        else if ((t) == 30) asm volatile("s_waitcnt vmcnt(0)" ::: "memory");  \
        asm volatile("s_waitcnt lgkmcnt(0)" ::: "memory");                    \
        __builtin_amdgcn_s_barrier();                                         \
        if ((t) < 31) RF256(Na, Nb, ((t) + 1) & 3);                           \
        MM256(Ca, Cb); }

    short8 Xa[8], Xb[4], Ya[8], Yb[4];
    STAGE256(0, 0);
    STAGE256(1, 1);
    STAGE256(2, 2);
    asm volatile("s_waitcnt vmcnt(8)" ::: "memory");
    __builtin_amdgcn_s_barrier();
    RF256(Xa, Xb, 0);
    for (int t2 = 0; t2 < 32; t2 += 2) {
        BODY256(t2, Xa, Xb, Ya, Yb);
        BODY256(t2 + 1, Ya, Yb, Xa, Xb);
    }
#undef STAGE256
#undef BODY256
}

// ---------------------------------------------------------------------------
// GEMM core (resident): 256x256 tile, 8 waves, 2 LDS bufs (64KB, 2 blocks/CU),
// 1-ahead prefetch w/ counted vmcnt(4), ds_read+MFMA in-phase (R7 schedule).
// Cross-block co-residency supplies the latency hiding the shallow pipeline loses.
// ---------------------------------------------------------------------------
__device__ __forceinline__ void gemm_core256_r(const u16* A, const u16* BT,
                                               int m0, int n0, f32x4 acc[8][4]) {
    __shared__ __align__(16) short As[2][256 * 32];
    __shared__ __align__(16) short Bs[2][256 * 32];
    const int tid = threadIdx.x;
    const int lane = tid & 63, w = tid >> 6;
    const int wr = w >> 2, wc = w & 3;
    const int ln15 = lane & 15, kch = lane >> 4;
    const int erow = tid >> 2;
    const int ecol = (((tid & 3) ^ ((tid >> 3) & 3)) << 3);

#define STAGE2R(buf, t)                                                       \
    {   const int k0_ = (t) * 32;                                             \
        _Pragma("unroll")                                                     \
        for (int rr = 0; rr < 2; ++rr) {                                      \
            gld_lds16(A  + (size_t)(m0 + rr * 128 + erow) * 1024 + k0_ + ecol,\
                      (short*)As[buf] + rr * 4096 + tid * 8);                 \
            gld_lds16(BT + (size_t)(n0 + rr * 128 + erow) * 1024 + k0_ + ecol,\
                      (short*)Bs[buf] + rr * 4096 + tid * 8);                 \
        } }

    STAGE2R(0, 0);
    for (int t = 0; t < 32; ++t) {
        const int cur = t & 1;
        if (t + 1 < 32) {
            STAGE2R(cur ^ 1, t + 1);                        // 1-ahead prefetch
            asm volatile("s_waitcnt vmcnt(4)" ::: "memory"); // tile t's 4 done; t+1 in flight
        } else {
            asm volatile("s_waitcnt vmcnt(0)" ::: "memory");
        }
        __builtin_amdgcn_sched_barrier(0);
        __builtin_amdgcn_s_barrier();
        {
            short8 Fa[8], Fb[4];
            RF256(Fa, Fb, cur);
            MM256(Fa, Fb);
        }
        asm volatile("s_waitcnt lgkmcnt(0)" ::: "memory");   // this wave's ds_reads retired
        __builtin_amdgcn_sched_barrier(0);
        __builtin_amdgcn_s_barrier();                        // buf[cur] free for reuse
    }
#undef STAGE2R
#undef RF256
#undef MM256
}

// XCD-bijective swizzle (nwg % 8 == 0)
__device__ __forceinline__ int xcd_swz(int lid, int nwg) {
    int q = nwg >> 3;
    return (lid & 7) * q + (lid >> 3);
}

__global__ __launch_bounds__(512, 2) void gemm_bf16(const u16* __restrict__ A,
                                                    const u16* __restrict__ BT,
                                                    float* __restrict__ C) {
    const int lid = blockIdx.y * 4 + blockIdx.x;
    const int sid = xcd_swz(lid, 128);
    const int m0 = (sid >> 2) * 256, n0 = (sid & 3) * 256;
    f32x4 acc[8][4] = {};
    gemm_core256(A, BT, m0, n0, acc);
    const int lane = threadIdx.x & 63, w = threadIdx.x >> 6;
    const int crow0 = m0 + (w >> 2) * 128 + (lane >> 4) * 4;
    const int ccol0 = n0 + (w & 3) * 64 + (lane & 15);
#pragma unroll
    for (int i = 0; i < 8; ++i)
#pragma unroll
        for (int j = 0; j < 4; ++j)
#pragma unroll
            for (int r = 0; r < 4; ++r)
                C[(size_t)(crow0 + i * 16 + r) * 1024 + ccol0 + j * 16] = acc[i][j][r];
}

__global__ __launch_bounds__(512, 2) void gemm_qkv(const u16* __restrict__ A,
                                                   const u16* __restrict__ WT0,
                                                   u16* __restrict__ xq16,
                                                   u16* __restrict__ xk16,
                                                   u16* __restrict__ xv16) {
    const int lid = blockIdx.y * 12 + blockIdx.x;
    const int sid = xcd_swz(lid, 384);
    const int lbx = sid % 12;
    const int which = lbx >> 2;
    const int n0 = (lbx & 3) * 256;
    const int m0 = (sid / 12) * 256;
    const u16* BT = WT0 + (size_t)which * 1048576;
    f32x4 acc[8][4] = {};
    gemm_core256_r(A, BT, m0, n0, acc);
    const int lane = threadIdx.x & 63, w = threadIdx.x >> 6;
    const int crow0 = m0 + (w >> 2) * 128 + (lane >> 4) * 4;
    const int ccol0 = n0 + (w & 3) * 64 + (lane & 15);
    u16* C16 = (which == 0) ? xq16 : (which == 1) ? xk16 : xv16;
#pragma unroll
    for (int i = 0; i < 8; ++i)
#pragma unroll
        for (int j = 0; j < 4; ++j)
#pragma unroll
            for (int r = 0; r < 4; ++r)
                C16[(size_t)(crow0 + i * 16 + r) * 1024 + ccol0 + j * 16] = f2bf(acc[i][j][r]);
}

// ---------------------------------------------------------------------------
// beta = sigmoid(x @ Wb) stored [B,H,L]; reads bf16 x
// ---------------------------------------------------------------------------
__global__ __launch_bounds__(256) void beta_k(const u16* __restrict__ X16,
                                              const float* __restrict__ Wb,
                                              float* __restrict__ beta) {
    int idx = blockIdx.x * 256 + threadIdx.x;
    int row = idx >> 4, h = idx & 15;
    const u16* xr = X16 + (size_t)row * DD;
    float s = 0.f;
    for (int k8 = 0; k8 < DD; k8 += 8) {
        short8 xv = *(const short8*)&xr[k8];
#pragma unroll
        for (int e = 0; e < 8; ++e)
            s += bf2f((u16)xv[e]) * Wb[(k8 + e) * HH + h];
    }
    float bv = 1.f / (1.f + expf(-s));
    int b = row >> 12, l = row & (LL - 1);
    beta[((size_t)b * HH + h) * LL + l] = bv;
}

// ---------------------------------------------------------------------------
// 3x fused conv, all bf16: which 0=q(norm) 1=k(norm) 2=v
// ---------------------------------------------------------------------------
__global__ __launch_bounds__(256) void conv3_k(const u16* __restrict__ xq16,
                                               const u16* __restrict__ xk16,
                                               const u16* __restrict__ xv16,
                                               const float* __restrict__ cwq,
                                               const float* __restrict__ cwk,
                                               const float* __restrict__ cwv,
                                               u16* __restrict__ q16,
                                               u16* __restrict__ k16,
                                               u16* __restrict__ v16) {
    const int which = blockIdx.z;
    const float* cw = (which == 0) ? cwq : (which == 1) ? cwk : cwv;
    const int l0 = blockIdx.x * 16, b = blockIdx.y;
    const int tid = threadIdx.x;
    const int d0 = tid * 4;
    const float4 w0 = *(const float4*)&cw[(d0 + 0) * 4];
    const float4 w1 = *(const float4*)&cw[(d0 + 1) * 4];
    const float4 w2 = *(const float4*)&cw[(d0 + 2) * 4];
    const float4 w3 = *(const float4*)&cw[(d0 + 3) * 4];
    const int h = d0 >> 6, hd = d0 & 63;
    const u16* Xb = ((which == 0) ? xq16 : (which == 1) ? xk16 : xv16) + (size_t)b * LL * DD;
    u16* O16 = (which == 0) ? q16 : (which == 1) ? k16 : v16;
    float4 xm3 = make_float4(0, 0, 0, 0), xm2 = xm3, xm1 = xm3;
    if (l0 > 0) {
        xm3 = ld_bf4(&Xb[(size_t)(l0 - 3) * DD + d0]);
        xm2 = ld_bf4(&Xb[(size_t)(l0 - 2) * DD + d0]);
        xm1 = ld_bf4(&Xb[(size_t)(l0 - 1) * DD + d0]);
    }
#pragma unroll
    for (int t = 0; t < 16; ++t) {
        const int l = l0 + t;
        float4 xc = ld_bf4(&Xb[(size_t)l * DD + d0]);
        float a0 = xm3.x * w0.x + xm2.x * w0.y + xm1.x * w0.z + xc.x * w0.w;
        float a1 = xm3.y * w1.x + xm2.y * w1.y + xm1.y * w1.z + xc.y * w1.w;
        float a2 = xm3.z * w2.x + xm2.z * w2.y + xm1.z * w2.z + xc.z * w2.w;
        float a3 = xm3.w * w3.x + xm2.w * w3.y + xm1.w * w3.z + xc.w * w3.w;
        a0 = a0 / (1.f + expf(-a0));
        a1 = a1 / (1.f + expf(-a1));
        a2 = a2 / (1.f + expf(-a2));
        a3 = a3 / (1.f + expf(-a3));
        if (which < 2) {
            float s = a0 * a0 + a1 * a1 + a2 * a2 + a3 * a3;
            s += __shfl_xor(s, 1);
            s += __shfl_xor(s, 2);
            s += __shfl_xor(s, 4);
            s += __shfl_xor(s, 8);
            float sc = rsqrtf(s);
            a0 *= sc; a1 *= sc; a2 *= sc; a3 *= sc;
        }
        uint2 o;
        o.x = (unsigned)f2bf(a0) | ((unsigned)f2bf(a1) << 16);
        o.y = (unsigned)f2bf(a2) | ((unsigned)f2bf(a3) << 16);
        *(uint2*)&O16[(((size_t)b * HH + h) * LL + l) * 64 + hd] = o;
        xm3 = xm2; xm2 = xm1; xm1 = xc;
    }
}

// ---------------------------------------------------------------------------
// Phase A: K,V exact bf16. W,U plain bf16 out. P,B plain fp32 out.
// ---------------------------------------------------------------------------
__global__ __launch_bounds__(256) void phaseA6(const u16* __restrict__ kg16,
                                               const u16* __restrict__ vg16,
                                               const float* __restrict__ betag,
                                               u16* __restrict__ Wg16,
                                               u16* __restrict__ UgT16,
                                               float* __restrict__ Pall,
                                               float* __restrict__ BallT) {
    __shared__ __align__(16) char pool[65536];
    u16* Kh   = (u16*)pool;              // 0-8K; later WTh
    u16* KTh  = (u16*)(pool + 8192);     // 8-16K (persists)
    float* At = (float*)(pool + 16384);  // 16-32K; later WTl/UTh
    float* WU = (float*)(pool + 32768);  // 32-64K; later scr/scrP
    u16* WTh  = (u16*)pool;
    u16* WTl  = (u16*)(pool + 16384);
    u16* UTh  = (u16*)(pool + 24576);
    float* scr  = (float*)(pool + 32768);  // B scratch (32-48K)
    float* scrP = (float*)(pool + 49152);  // P scratch (48-64K)

    const int c = blockIdx.x, bh = blockIdx.y;
    const int tid = threadIdx.x, lane = tid & 63, w = tid >> 6;
    const int g = lane >> 4, ln = lane & 15;
    const int t0 = (tid >> 4) * 4, d4 = (tid & 15) * 4;
    const size_t base = ((size_t)bh * LL + (size_t)c * 64) * 64;
    const size_t obase = ((size_t)bh * NC + c) * 4096;
    const float* bet = betag + (size_t)bh * LL + (size_t)c * 64;

    // 1a. K (bf16) -> Kh swizzled
    g_to_ls_b(kg16 + base, Kh, tid);
    // 1b. K^T -> KTh (global re-read 4x4, packed transposed stores)
    {
        u16 kv[4][4];
#pragma unroll
        for (int i = 0; i < 4; ++i) {
            uint2 v = *(const uint2*)&kg16[base + (size_t)(t0 + i) * 64 + d4];
            kv[i][0] = (u16)v.x; kv[i][1] = (u16)(v.x >> 16);
            kv[i][2] = (u16)v.y; kv[i][3] = (u16)(v.y >> 16);
        }
#pragma unroll
        for (int j = 0; j < 4; ++j) {
            uint2 hv;
            hv.x = (unsigned)kv[0][j] | ((unsigned)kv[1][j] << 16);
            hv.y = (unsigned)kv[2][j] | ((unsigned)kv[3][j] << 16);
            *(uint2*)&KTh[swze(d4 + j, t0)] = hv;
        }
    }
    __syncthreads();
    // 2. Gram A = strict_tril(beta * K K^T)
    {
        f32x4 acc[4] = {};
        mm64_bb(Kh, Kh, acc, w, lane);
#pragma unroll
        for (int r = 0; r < 4; ++r) {
            int t = w * 16 + g * 4 + r;
            float bt = bet[t];
#pragma unroll
            for (int j = 0; j < 4; ++j) {
                int s = j * 16 + ln;
                At[t * 64 + s] = (s < t) ? bt * acc[j][r] : 0.f;
            }
        }
    }
    // 3. RHS: WU[t][j] = beta_t * (j<64 ? K[t][j] : V[t][j-64])
#pragma unroll
    for (int p = 0; p < 8; ++p) {
        int flat = p * 1024 + tid * 4;
        int t = flat >> 7, j = flat & 127;
        float bt = bet[t];
        float4 src;
        if (j < 64) src = ld_bf4(&Kh[swze(t, j)]);
        else        src = ld_bf4(&vg16[base + (size_t)t * 64 + (j - 64)]);
        src.x *= bt; src.y *= bt; src.z *= bt; src.w *= bt;
        *(float4*)&WU[t * 128 + j] = src;
    }
    __syncthreads();
    // 4. blocked forward substitution (panels of 16)
#pragma unroll
    for (int pb = 0; pb < 4; ++pb) {
        const int r0 = pb * 16;
        if (pb > 0) {
            const int col = tid & 127;
            const int rbase = r0 + (tid >> 7) * 8;
            float acc8[8] = {};
            for (int r = 0; r < r0; r += 4) {
                float u0 = WU[(r + 0) * 128 + col], u1 = WU[(r + 1) * 128 + col];
                float u2 = WU[(r + 2) * 128 + col], u3 = WU[(r + 3) * 128 + col];
#pragma unroll
                for (int i = 0; i < 8; ++i) {
                    float4 a4 = *(const float4*)&At[(rbase + i) * 64 + r];
                    acc8[i] += a4.x * u0 + a4.y * u1 + a4.z * u2 + a4.w * u3;
                }
            }
#pragma unroll
            for (int i = 0; i < 8; ++i) WU[(rbase + i) * 128 + col] -= acc8[i];
            __syncthreads();
        }
        if (tid < 128) {
            const int col = tid;
            float wv[16];
            wv[0] = WU[r0 * 128 + col];
#pragma unroll
            for (int t = 1; t < 16; ++t) {
                float a = WU[(r0 + t) * 128 + col];
#pragma unroll
                for (int r = 0; r < t; ++r) a -= At[(r0 + t) * 64 + r0 + r] * wv[r];
                wv[t] = a;
            }
#pragma unroll
            for (int t = 1; t < 16; ++t) WU[(r0 + t) * 128 + col] = wv[t];
        }
        __syncthreads();
    }
    // 5a. Wg16 global write (plain bf16, coalesced uint2)
#pragma unroll
    for (int p = 0; p < 4; ++p) {
        int flat = p * 1024 + tid * 4;
        int t = flat >> 6, j = flat & 63;
        float4 v = *(const float4*)&WU[t * 128 + j];
        uint2 o;
        o.x = (unsigned)f2bf(v.x) | ((unsigned)f2bf(v.y) << 16);
        o.y = (unsigned)f2bf(v.z) | ((unsigned)f2bf(v.w) << 16);
        *(uint2*)&Wg16[obase + flat] = o;
    }
    // 5b. W^T split build + U^T plain-bf16 build (transposed packed stores)
    {
        u16 h4[4][4], l4[4][4];
#pragma unroll
        for (int i = 0; i < 4; ++i) {
            float4 v = *(const float4*)&WU[(t0 + i) * 128 + d4];
            split2(v.x, h4[i][0], l4[i][0]); split2(v.y, h4[i][1], l4[i][1]);
            split2(v.z, h4[i][2], l4[i][2]); split2(v.w, h4[i][3], l4[i][3]);
        }
#pragma unroll
        for (int j = 0; j < 4; ++j) {
            uint2 hv, lv;
            hv.x = (unsigned)h4[0][j] | ((unsigned)h4[1][j] << 16);
            hv.y = (unsigned)h4[2][j] | ((unsigned)h4[3][j] << 16);
            lv.x = (unsigned)l4[0][j] | ((unsigned)l4[1][j] << 16);
            lv.y = (unsigned)l4[2][j] | ((unsigned)l4[3][j] << 16);
            *(uint2*)&WTh[swze(d4 + j, t0)] = hv;
            *(uint2*)&WTl[swze(d4 + j, t0)] = lv;
        }
#pragma unroll
        for (int i = 0; i < 4; ++i) {
            float4 v = *(const float4*)&WU[(t0 + i) * 128 + 64 + d4];
            h4[i][0] = f2bf(v.x); h4[i][1] = f2bf(v.y);
            h4[i][2] = f2bf(v.z); h4[i][3] = f2bf(v.w);
        }
#pragma unroll
        for (int j = 0; j < 4; ++j) {
            uint2 hv;
            hv.x = (unsigned)h4[0][j] | ((unsigned)h4[1][j] << 16);
            hv.y = (unsigned)h4[2][j] | ((unsigned)h4[3][j] << 16);
            *(uint2*)&UTh[swze(d4 + j, t0)] = hv;
        }
    }
    __syncthreads();
    // 6. UgT16 global write (plain bf16 from UTh, coalesced short8)
#pragma unroll
    for (int p = 0; p < 2; ++p) {
        int flat = p * 2048 + tid * 8;
        int n = flat >> 6, tt = flat & 63;
        *(short8*)&UgT16[obase + flat] = *(const short8*)&UTh[swze(n, tt)];
    }
    // 7. P = I - K^T W (split W); B = K^T U (U exact, 1-term)
    f32x4 aP[4] = {}, aB[4] = {};
    mm64_ab(KTh, WTh, WTl, aP, w, lane);
    mm64_bb(KTh, UTh, aB, w, lane);
#pragma unroll
    for (int j = 0; j < 4; ++j)
#pragma unroll
        for (int r = 0; r < 4; ++r) {
            int row = w * 16 + g * 4 + r, col = j * 16 + ln;
            scrP[swz(row, col)] = ((row == col) ? 1.f : 0.f) - aP[j][r];
            scr[swz(row, col)] = aB[j][r];
        }
    __syncthreads();
    // 8. Pall (plain) + BallT (transposed), both coalesced fp32 float4 streams
#pragma unroll
    for (int p = 0; p < 4; ++p) {
        int flat = p * 1024 + tid * 4;
        int rr = flat >> 6, cc = flat & 63;
        float4 op = make_float4(scrP[swz(rr, cc + 0)], scrP[swz(rr, cc + 1)],
                                scrP[swz(rr, cc + 2)], scrP[swz(rr, cc + 3)]);
        *(float4*)&Pall[obase + flat] = op;
        float4 ob4 = make_float4(scr[swz(cc + 0, rr)], scr[swz(cc + 1, rr)],
                                 scr[swz(cc + 2, rr)], scr[swz(cc + 3, rr)]);
        *(float4*)&BallT[obase + flat] = ob4;
    }
}

// ---------------------------------------------------------------------------
// compose4: fp32 I/O + T14 register prefetch of next P tile.
// ---------------------------------------------------------------------------
__global__ __launch_bounds__(256) void compose4(const float* __restrict__ Pall,
                                                const float* __restrict__ BallT,
                                                float* __restrict__ Pg,
                                                float* __restrict__ BgT) {
    __shared__ __align__(16) char pool[81920];
    u16* Ph = (u16*)pool;
    u16* Pl = (u16*)(pool + 8192);
    u16* Bh = (u16*)(pool + 16384);
    u16* Bl = (u16*)(pool + 24576);
    u16* nh = (u16*)(pool + 32768);
    u16* nl = (u16*)(pool + 40960);
    float* scr = (float*)(pool + 49152);
    const int g = blockIdx.x, bh = blockIdx.y;
    const int tid = threadIdx.x, lane = tid & 63, w = tid >> 6;
    const int gi = lane >> 4, ln = lane & 15;
    const size_t base0 = ((size_t)bh * NC + (size_t)g * GS) * 4096;
    f32x4 mP[4], mB[4];
#pragma unroll
    for (int p = 0; p < 4; ++p) {
        int flat = p * 1024 + tid * 4;
        int r = flat >> 6, c4 = flat & 63;
        *(float4*)&scr[swz(r, c4)] = *(const float4*)&Pall[base0 + flat];
    }
    g_to_frag(BallT + base0, mB, w, lane);
    __syncthreads();
#pragma unroll
    for (int j = 0; j < 4; ++j)
#pragma unroll
        for (int r = 0; r < 4; ++r) {
            int row = w * 16 + gi * 4 + r, col = j * 16 + ln;
            mP[j][r] = scr[swz(col, row)];
        }
    float4 pf[4];
    pload_f(pf, Pall + base0 + 4096, tid);
    for (int s = 1; s < GS; ++s) {
        __syncthreads();
        frag_to_ls(mP, Ph, Pl, w, lane);
        frag_to_ls(mB, Bh, Bl, w, lane);
        pstore_ls_f(pf, nh, nl, tid);
        __syncthreads();
        if (s < GS - 1) pload_f(pf, Pall + base0 + (size_t)(s + 1) * 4096, tid);
        f32x4 aP[4] = {}, aB[4] = {};
        mm64(Ph, Pl, nh, nl, aP, w, lane);
        mm64(Bh, Bl, nh, nl, aB, w, lane);
        g_add_frag(BallT + base0 + (size_t)s * 4096, aB, w, lane);
#pragma unroll
        for (int j = 0; j < 4; ++j) { mP[j] = aP[j]; mB[j] = aB[j]; }
    }
    const size_t gbase = ((size_t)bh * GG + g) * 4096;
    frag_to_g(mB, BgT + gbase, w, lane);
    __syncthreads();
#pragma unroll
    for (int j = 0; j < 4; ++j)
#pragma unroll
        for (int r = 0; r < 4; ++r) {
            int row = w * 16 + gi * 4 + r, col = j * 16 + ln;
            scr[swz(row, col)] = mP[j][r];
        }
    __syncthreads();
#pragma unroll
    for (int p = 0; p < 4; ++p) {
        int flat = p * 1024 + tid * 4;
        int a = flat >> 6, b0 = flat & 63;
        float4 o = make_float4(scr[swz(b0 + 0, a)], scr[swz(b0 + 1, a)],
                               scr[swz(b0 + 2, a)], scr[swz(b0 + 3, a)]);
        *(float4*)&Pg[gbase + flat] = o;
    }
}

// ---------------------------------------------------------------------------
// scanG4: fp32 I/O.
// ---------------------------------------------------------------------------
__global__ __launch_bounds__(256) void scanG4(const float* __restrict__ Pg,
                                              const float* __restrict__ BgT,
                                              float* __restrict__ SallT) {
    __shared__ __align__(16) char pool[32768];
    u16* Sh = (u16*)pool;
    u16* Sl = (u16*)(pool + 8192);
    u16* nh = (u16*)(pool + 16384);
    u16* nl = (u16*)(pool + 24576);
    const int bh = blockIdx.x;
    const int tid = threadIdx.x, lane = tid & 63, w = tid >> 6;
    f32x4 mS[4] = {};
    for (int g = 0; g < GG; ++g) {
        const size_t sbase = ((size_t)bh * NC + (size_t)g * GS) * 4096;
        frag_to_g(mS, SallT + sbase, w, lane);
        if (g == GG - 1) break;
        __syncthreads();
        frag_to_ls(mS, Sh, Sl, w, lane);
        g_to_ls(Pg + ((size_t)bh * GG + g) * 4096, nh, nl, tid);
        __syncthreads();
        f32x4 a[4] = {};
        mm64(Sh, Sl, nh, nl, a, w, lane);
        g_add_frag(BgT + ((size_t)bh * GG + g) * 4096, a, w, lane);
#pragma unroll
        for (int j = 0; j < 4; ++j) mS[j] = a[j];
    }
}

// ---------------------------------------------------------------------------
// rollout4: fp32 I/O + T14 register prefetch.
// ---------------------------------------------------------------------------
__global__ __launch_bounds__(256) void rollout4(const float* __restrict__ Pall,
                                                const float* __restrict__ BallT,
                                                float* __restrict__ SallT) {
    __shared__ __align__(16) char pool[32768];
    u16* Sh = (u16*)pool;
    u16* Sl = (u16*)(pool + 8192);
    u16* nh = (u16*)(pool + 16384);
    u16* nl = (u16*)(pool + 24576);
    const int g = blockIdx.x, bh = blockIdx.y;
    const int tid = threadIdx.x, lane = tid & 63, w = tid >> 6;
    const size_t base0 = ((size_t)bh * NC + (size_t)g * GS) * 4096;
    f32x4 mS[4];
    g_to_frag(SallT + base0, mS, w, lane);
    float4 pf[4];
    pload_f(pf, Pall + base0, tid);
    for (int j = 1; j < GS; ++j) {
        __syncthreads();
        frag_to_ls(mS, Sh, Sl, w, lane);
        pstore_ls_f(pf, nh, nl, tid);
        __syncthreads();
        if (j < GS - 1) pload_f(pf, Pall + base0 + (size_t)j * 4096, tid);
        f32x4 a[4] = {};
        mm64(Sh, Sl, nh, nl, a, w, lane);
        g_add_frag(BallT + base0 + (size_t)(j - 1) * 4096, a, w, lane);
#pragma unroll
        for (int jj = 0; jj < 4; ++jj) mS[jj] = a[jj];
        frag_to_g(mS, SallT + base0 + (size_t)j * 4096, w, lane);
    }
}

// ---------------------------------------------------------------------------
// phaseO6: W,U plain bf16 (U staged to LDS); S fp32; Q,K exact bf16.
// M=causal(QK^T); Delta^T = U^T - (WS)^T; O = QS + M*Delta; fused RMSNorm.
// ---------------------------------------------------------------------------
__global__ __launch_bounds__(256) void phaseO6(const u16* __restrict__ Wg16,
                                               const u16* __restrict__ UgT16,
                                               const u16* __restrict__ qg16,
                                               const u16* __restrict__ kg16,
                                               const float* __restrict__ SallT,
                                               const float* __restrict__ nw,
                                               u16* __restrict__ ob) {
    __shared__ __align__(16) char pool[65536];
    u16* Qh = (u16*)pool;               // 8K
    u16* Kh = (u16*)(pool + 8192);      // 8K; later Dh
    u16* Wh = (u16*)(pool + 16384);     // 8K; later Mh
    u16* Wl = (u16*)(pool + 24576);     // 8K; Ml
    u16* Sh = (u16*)(pool + 32768);
    u16* Sl = (u16*)(pool + 40960);
    u16* Dl = (u16*)(pool + 49152);     // 8K
    u16* Uh = (u16*)(pool + 57344);     // 8K staged U^T
    u16* Dh = Kh;
    u16* Mh = Wh; u16* Ml = Wl;
    const int c = blockIdx.x, bh = blockIdx.y;
    const int b = bh >> 4, h = bh & 15;
    const int tid = threadIdx.x, lane = tid & 63, w = tid >> 6;
    const int gi = lane >> 4, ln = lane & 15;
    const size_t tbase = ((size_t)bh * NC + c) * 4096;
    const size_t qkbase = ((size_t)bh * LL + (size_t)c * 64) * 64;
    g_to_ls_b(qg16 + qkbase, Qh, tid);
    g_to_ls_b(kg16 + qkbase, Kh, tid);
    g_to_ls_b(Wg16 + tbase, Wh, tid);
    g_to_ls_b(UgT16 + tbase, Uh, tid);
    g_to_ls(SallT + tbase, Sh, Sl, tid);
    __syncthreads();
    f32x4 aM[4] = {}, aD[4] = {};
    mm64_bb(Qh, Kh, aM, w, lane);        // Q K^T
    mm64_sb(Sh, Sl, Wh, aD, w, lane);    // (W S)^T   (S split, W exact)
    __syncthreads();                     // all K/W reads done
#pragma unroll
    for (int j = 0; j < 4; ++j)
#pragma unroll
        for (int r = 0; r < 4; ++r) {
            int row = w * 16 + gi * 4 + r, col = j * 16 + ln;
            float mv = (col <= row) ? aM[j][r] : 0.f;
            u16 mh_, ml_; split2(mv, mh_, ml_);
            Mh[swze(row, col)] = mh_;
            Ml[swze(row, col)] = ml_;
            float dv = bf2f(Uh[swze(row, col)]) - aD[j][r];
            u16 dh_, dl_; split2(dv, dh_, dl_);
            Dh[swze(row, col)] = dh_;
            Dl[swze(row, col)] = dl_;
        }
    __syncthreads();
    f32x4 aO[4] = {};
    mm64_ab(Qh, Sh, Sl, aO, w, lane);    // Q S
    mm64(Mh, Ml, Dh, Dl, aO, w, lane);   // + M Delta
    float nwv[4];
#pragma unroll
    for (int j = 0; j < 4; ++j) nwv[j] = nw[j * 16 + ln];
#pragma unroll
    for (int r = 0; r < 4; ++r) {
        float ss = 0.f;
#pragma unroll
        for (int j = 0; j < 4; ++j) ss += aO[j][r] * aO[j][r];
        ss += __shfl_xor(ss, 1);
        ss += __shfl_xor(ss, 2);
        ss += __shfl_xor(ss, 4);
        ss += __shfl_xor(ss, 8);
        float rms = rsqrtf(ss * (1.f / 64.f) + 1e-5f);
        int row = w * 16 + gi * 4 + r;
        size_t orow = ((size_t)b * LL + (size_t)c * 64 + row) * DD + (size_t)h * 64;
#pragma unroll
        for (int j = 0; j < 4; ++j)
            ob[orow + j * 16 + ln] = f2bf(aO[j][r] * rms * nwv[j]);
    }
}

// ---------------------------------------------------------------------------
extern "C" void kernel_launch(void* const* d_in, const int* in_sizes, int n_in,
                              void* d_out, int out_size, void* d_ws, size_t ws_size,
                              hipStream_t stream) {
    const float* x  = (const float*)d_in[0];
    const float* Wq = (const float*)d_in[1];
    const float* Wk = (const float*)d_in[2];
    const float* Wv = (const float*)d_in[3];
    const float* Wb = (const float*)d_in[4];
    const float* cq = (const float*)d_in[5];
    const float* ck = (const float*)d_in[6];
    const float* cv = (const float*)d_in[7];
    const float* nw = (const float*)d_in[8];
    const float* Wo = (const float*)d_in[9];
    float* out = (float*)d_out;
    float* ws = (float*)d_ws;

    const size_t SZ = (size_t)BB * LL * DD;   // 8388608
    u16* xv16    = (u16*)ws;        // gemm v out; slab reused as Pall
    u16* v16     = (u16*)(ws + SZ); // conv v out; slab reused as ob
    u16* Wg16    = (u16*)(ws + 2 * SZ);       // plain bf16 W tiles
    u16* UgT16   = (u16*)(ws + 2 * SZ) + SZ;  // plain bf16 U^T tiles
    float* SallT = ws + 4 * SZ;
    u16* xb   = (u16*)(ws + 5 * SZ);          // x bf16; dead after conv/beta
    u16* q16  = xb;                           // conv q out (reuses xb)
    u16* xq16 = (u16*)(ws + 5 * SZ) + SZ;
    u16* xk16 = (u16*)(ws + 5 * SZ) + 2 * SZ;
    u16* k16  = (u16*)(ws + 5 * SZ) + 3 * SZ;
    float* beta = ws + 7 * SZ;                        // 131072 floats
    u16* wqT  = (u16*)(beta + (size_t)BH * LL);       // 4M u16 (q,k,v,o)
    float* Pg  = (float*)(wqT + (size_t)4 * 1048576); // 1M floats
    float* BgT = Pg + 1048576;                        // 1M floats

    float* Pall  = ws;        // overwrites xv16 (dead after conv3)
    float* BallT = out;       // d_out as scratch; fully overwritten by final GEMM
    u16* ob   = (u16*)(ws + SZ);   // overwrites v16 (dead after phaseA6)
    u16* woT  = wqT + (size_t)3 * 1048576;

    dim3 blk(256);

    prep_k<<<dim3(8192), blk, 0, stream>>>(x, xb, Wq, Wk, Wv, Wo, wqT);
    gemm_qkv<<<dim3(12, 32), dim3(512), 0, stream>>>(xb, wqT, xq16, xk16, xv16);
    beta_k<<<dim3(512), blk, 0, stream>>>(xb, Wb, beta);
    conv3_k<<<dim3(LL / 16, BB, 3), blk, 0, stream>>>(xq16, xk16, xv16, cq, ck, cv, q16, k16, v16);
    phaseA6<<<dim3(NC, BH), blk, 0, stream>>>(k16, v16, beta, Wg16, UgT16, Pall, BallT);
    compose4<<<dim3(GG, BH), blk, 0, stream>>>(Pall, BallT, Pg, BgT);
    scanG4<<<dim3(BH), blk, 0, stream>>>(Pg, BgT, SallT);
    rollout4<<<dim3(GG, BH), blk, 0, stream>>>(Pall, BallT, SallT);
    phaseO6<<<dim3(NC, BH), blk, 0, stream>>>(Wg16, UgT16, q16, k16, SallT, nw, ob);
    gemm_bf16<<<dim3(4, 32), dim3(512), 0, stream>>>(ob, woT, out);
}

// Round 18
// 319.759 us; speedup vs baseline: 1.0568x; 1.0568x over previous
//
#include <hip/hip_runtime.h>
#include <hip/hip_bf16.h>
#include <math.h>

#define BB 2
#define LL 4096
#define DD 1024
#define HH 16
#define HDIM 64
#define CC 64
#define NC 64   // LL/CC
#define BH 32   // BB*HH
#define GG 8    // chunk groups
#define GS 8    // chunks per group

typedef __attribute__((ext_vector_type(8))) short short8;
typedef __attribute__((ext_vector_type(4))) float f32x4;
typedef unsigned short u16;
typedef unsigned int u32;

__device__ __forceinline__ u16 f2bf(float f) {
    unsigned int u = __float_as_uint(f);
    unsigned int r = (u + 0x7fffu + ((u >> 16) & 1u)) >> 16;
    return (u16)r;
}
__device__ __forceinline__ float bf2f(u16 h) {
    return __uint_as_float((unsigned)h << 16);
}
__device__ __forceinline__ void split2(float x, u16& h, u16& l) {
    h = f2bf(x);
    l = f2bf(x - bf2f(h));
}
__device__ __forceinline__ float4 ld_bf4(const u16* p) {
    uint2 v = *(const uint2*)p;
    return make_float4(bf2f((u16)v.x), bf2f((u16)(v.x >> 16)),
                       bf2f((u16)v.y), bf2f((u16)(v.y >> 16)));
}

__device__ __forceinline__ void gld_lds16(const void* g, void* l) {
    __builtin_amdgcn_global_load_lds(
        (const __attribute__((address_space(1))) void*)g,
        (__attribute__((address_space(3))) void*)l, 16, 0, 0);
}

// fp32 [64][64] tile swizzle (4-elem chunks XOR'd by row>>2)
__device__ __forceinline__ int swz(int r, int c) {
    return (r << 6) + ((((c >> 2) ^ (r >> 2)) & 15) << 2) + (c & 3);
}
// bf16 [64][64] tile swizzle (reads + stride-4 transposed writes both 2-way)
__device__ __forceinline__ int swze(int r, int c) {
    return (r << 6) + (c ^ (((r ^ (r >> 3)) & 7) << 3));
}

// ---------------------------------------------------------------------------
// mm64 variants: C[a][b] += sum_k A[a][k]*B[b][k]; A,B in swizzled LDS tiles.
// ---------------------------------------------------------------------------
__device__ __forceinline__ void mm64(const u16* __restrict__ Ah, const u16* __restrict__ Al,
                                     const u16* __restrict__ Bh, const u16* __restrict__ Bl,
                                     f32x4* acc, int w, int lane) {
    const int ln = lane & 15, kg = (lane >> 4) * 8;
#pragma unroll
    for (int kb = 0; kb < 2; ++kb) {
        const int k0 = kb * 32 + kg;
        short8 ah = *(const short8*)&Ah[swze(w * 16 + ln, k0)];
        short8 al = *(const short8*)&Al[swze(w * 16 + ln, k0)];
#pragma unroll
        for (int j = 0; j < 4; ++j) {
            short8 bh = *(const short8*)&Bh[swze(j * 16 + ln, k0)];
            short8 bl = *(const short8*)&Bl[swze(j * 16 + ln, k0)];
            acc[j] = __builtin_amdgcn_mfma_f32_16x16x32_bf16(ah, bh, acc[j], 0, 0, 0);
            acc[j] = __builtin_amdgcn_mfma_f32_16x16x32_bf16(ah, bl, acc[j], 0, 0, 0);
            acc[j] = __builtin_amdgcn_mfma_f32_16x16x32_bf16(al, bh, acc[j], 0, 0, 0);
        }
    }
}
// both operands exact bf16
__device__ __forceinline__ void mm64_bb(const u16* __restrict__ Ah,
                                        const u16* __restrict__ Bh,
                                        f32x4* acc, int w, int lane) {
    const int ln = lane & 15, kg = (lane >> 4) * 8;
#pragma unroll
    for (int kb = 0; kb < 2; ++kb) {
        const int k0 = kb * 32 + kg;
        short8 ah = *(const short8*)&Ah[swze(w * 16 + ln, k0)];
#pragma unroll
        for (int j = 0; j < 4; ++j) {
            short8 bh = *(const short8*)&Bh[swze(j * 16 + ln, k0)];
            acc[j] = __builtin_amdgcn_mfma_f32_16x16x32_bf16(ah, bh, acc[j], 0, 0, 0);
        }
    }
}
// A exact bf16, B split
__device__ __forceinline__ void mm64_ab(const u16* __restrict__ Ah,
                                        const u16* __restrict__ Bh, const u16* __restrict__ Bl,
                                        f32x4* acc, int w, int lane) {
    const int ln = lane & 15, kg = (lane >> 4) * 8;
#pragma unroll
    for (int kb = 0; kb < 2; ++kb) {
        const int k0 = kb * 32 + kg;
        short8 ah = *(const short8*)&Ah[swze(w * 16 + ln, k0)];
#pragma unroll
        for (int j = 0; j < 4; ++j) {
            short8 bh = *(const short8*)&Bh[swze(j * 16 + ln, k0)];
            short8 bl = *(const short8*)&Bl[swze(j * 16 + ln, k0)];
            acc[j] = __builtin_amdgcn_mfma_f32_16x16x32_bf16(ah, bh, acc[j], 0, 0, 0);
            acc[j] = __builtin_amdgcn_mfma_f32_16x16x32_bf16(ah, bl, acc[j], 0, 0, 0);
        }
    }
}
// A split, B exact bf16
__device__ __forceinline__ void mm64_sb(const u16* __restrict__ Ah, const u16* __restrict__ Al,
                                        const u16* __restrict__ Bh,
                                        f32x4* acc, int w, int lane) {
    const int ln = lane & 15, kg = (lane >> 4) * 8;
#pragma unroll
    for (int kb = 0; kb < 2; ++kb) {
        const int k0 = kb * 32 + kg;
        short8 ah = *(const short8*)&Ah[swze(w * 16 + ln, k0)];
        short8 al = *(const short8*)&Al[swze(w * 16 + ln, k0)];
#pragma unroll
        for (int j = 0; j < 4; ++j) {
            short8 bh = *(const short8*)&Bh[swze(j * 16 + ln, k0)];
            acc[j] = __builtin_amdgcn_mfma_f32_16x16x32_bf16(ah, bh, acc[j], 0, 0, 0);
            acc[j] = __builtin_amdgcn_mfma_f32_16x16x32_bf16(al, bh, acc[j], 0, 0, 0);
        }
    }
}

// global bf16 [64][64] -> swizzled LDS copy
__device__ __forceinline__ void g_to_ls_b(const u16* __restrict__ G16, u16* Ah, int tid) {
#pragma unroll
    for (int p = 0; p < 2; ++p) {
        int flat = p * 2048 + tid * 8;
        int r = flat >> 6, c = flat & 63;
        *(short8*)&Ah[swze(r, c)] = *(const short8*)&G16[flat];
    }
}

// global fp32 [64][64] -> hi/lo bf16 LDS (split at consumer)
__device__ __forceinline__ void g_to_ls(const float* __restrict__ G, u16* Ah, u16* Al, int tid) {
#pragma unroll
    for (int p = 0; p < 4; ++p) {
        int flat = p * 1024 + tid * 4;
        int r = flat >> 6, c = flat & 63;
        float4 v = *(const float4*)&G[flat];
        u16 h0, l0, h1, l1, h2, l2, h3, l3;
        split2(v.x, h0, l0); split2(v.y, h1, l1);
        split2(v.z, h2, l2); split2(v.w, h3, l3);
        int idx = swze(r, c);
        uint2 hv, lv;
        hv.x = (unsigned)h0 | ((unsigned)h1 << 16); hv.y = (unsigned)h2 | ((unsigned)h3 << 16);
        lv.x = (unsigned)l0 | ((unsigned)l1 << 16); lv.y = (unsigned)l2 | ((unsigned)l3 << 16);
        *(uint2*)&Ah[idx] = hv;
        *(uint2*)&Al[idx] = lv;
    }
}

// fp32 global: register prefetch + split LDS store (T14)
__device__ __forceinline__ void pload_f(float4 pf[4], const float* __restrict__ G, int tid) {
    pf[0] = *(const float4*)&G[tid * 8];
    pf[1] = *(const float4*)&G[tid * 8 + 4];
    pf[2] = *(const float4*)&G[2048 + tid * 8];
    pf[3] = *(const float4*)&G[2048 + tid * 8 + 4];
}
__device__ __forceinline__ void pstore_ls_f(const float4 pf[4], u16* Ah, u16* Al, int tid) {
#pragma unroll
    for (int p = 0; p < 2; ++p) {
        int flat = p * 2048 + tid * 8;
        int r = flat >> 6, c = flat & 63;
        float4 a = pf[2 * p], b = pf[2 * p + 1];
        u16 h[8], l[8];
        split2(a.x, h[0], l[0]); split2(a.y, h[1], l[1]);
        split2(a.z, h[2], l[2]); split2(a.w, h[3], l[3]);
        split2(b.x, h[4], l[4]); split2(b.y, h[5], l[5]);
        split2(b.z, h[6], l[6]); split2(b.w, h[7], l[7]);
        short8 hi, lo;
#pragma unroll
        for (int e = 0; e < 8; ++e) { hi[e] = (short)h[e]; lo[e] = (short)l[e]; }
        *(short8*)&Ah[swze(r, c)] = hi;
        *(short8*)&Al[swze(r, c)] = lo;
    }
}

// register frag -> hi/lo bf16 LDS
__device__ __forceinline__ void frag_to_ls(const f32x4* acc, u16* Ah, u16* Al, int w, int lane) {
    const int g = lane >> 4, ln = lane & 15;
#pragma unroll
    for (int j = 0; j < 4; ++j)
#pragma unroll
        for (int r = 0; r < 4; ++r) {
            int row = w * 16 + g * 4 + r, col = j * 16 + ln;
            u16 h, l; split2(acc[j][r], h, l);
            Ah[swze(row, col)] = h;
            Al[swze(row, col)] = l;
        }
}

// fp32-global frag helpers
__device__ __forceinline__ void g_to_frag(const float* __restrict__ G, f32x4* acc, int w, int lane) {
    const int g = lane >> 4, ln = lane & 15;
#pragma unroll
    for (int j = 0; j < 4; ++j)
#pragma unroll
        for (int r = 0; r < 4; ++r)
            acc[j][r] = G[(w * 16 + g * 4 + r) * 64 + j * 16 + ln];
}
__device__ __forceinline__ void g_add_frag(const float* __restrict__ G, f32x4* acc, int w, int lane) {
    const int g = lane >> 4, ln = lane & 15;
#pragma unroll
    for (int j = 0; j < 4; ++j)
#pragma unroll
        for (int r = 0; r < 4; ++r)
            acc[j][r] += G[(w * 16 + g * 4 + r) * 64 + j * 16 + ln];
}
__device__ __forceinline__ void frag_to_g(const f32x4* acc, float* __restrict__ G, int w, int lane) {
    const int g = lane >> 4, ln = lane & 15;
#pragma unroll
    for (int j = 0; j < 4; ++j)
#pragma unroll
        for (int r = 0; r < 4; ++r)
            G[(w * 16 + g * 4 + r) * 64 + j * 16 + ln] = acc[j][r];
}

// ---------------------------------------------------------------------------
// prep: fused fp32->bf16 cast of x (bid<4096) + 4x W transpose-cast (else)
// ---------------------------------------------------------------------------
__global__ __launch_bounds__(256) void prep_k(const float* __restrict__ in,
                                              u16* __restrict__ out,
                                              const float* __restrict__ W0,
                                              const float* __restrict__ W1,
                                              const float* __restrict__ W2,
                                              const float* __restrict__ W3,
                                              u16* __restrict__ WT0) {
    __shared__ float t[32][33];
    const int bid = blockIdx.x;
    if (bid < 4096) {
        int i = (bid * 256 + threadIdx.x) * 8;
        float4 a = *(const float4*)&in[i];
        float4 b = *(const float4*)&in[i + 4];
        uint4 o;
        o.x = (unsigned)f2bf(a.x) | ((unsigned)f2bf(a.y) << 16);
        o.y = (unsigned)f2bf(a.z) | ((unsigned)f2bf(a.w) << 16);
        o.z = (unsigned)f2bf(b.x) | ((unsigned)f2bf(b.y) << 16);
        o.w = (unsigned)f2bf(b.z) | ((unsigned)f2bf(b.w) << 16);
        *(uint4*)&out[i] = o;
        return;
    }
    const int t2 = bid - 4096;
    const int which = t2 >> 10, rem = t2 & 1023;
    const int bx = (rem & 31) * 32, by = (rem >> 5) * 32;
    const float* W = (which == 0) ? W0 : (which == 1) ? W1 : (which == 2) ? W2 : W3;
    u16* WT = WT0 + (size_t)which * 1048576;
#pragma unroll
    for (int p = 0; p < 4; ++p) {
        int idx = p * 256 + threadIdx.x;
        int r = idx >> 5, cc = idx & 31;
        t[r][cc] = W[(size_t)(by + r) * 1024 + bx + cc];
    }
    __syncthreads();
#pragma unroll
    for (int p = 0; p < 4; ++p) {
        int idx = p * 256 + threadIdx.x;
        int r = idx >> 5, cc = idx & 31;
        WT[(size_t)(bx + r) * 1024 + by + cc] = f2bf(t[cc][r]);
    }
}

// ---------------------------------------------------------------------------
// GEMM core v4: 256x256 tile, 8 waves, wave-tile 128x64, BK=32, 4 LDS bufs,
// 3-ahead prefetch with counted vmcnt, one barrier per K-step, frag ping-pong.
// ---------------------------------------------------------------------------
__device__ __forceinline__ void gemm_core256(const u16* A, const u16* BT,
                                             int m0, int n0, f32x4 acc[8][4]) {
    __shared__ __align__(16) short As[4][256 * 32];
    __shared__ __align__(16) short Bs[4][256 * 32];
    const int tid = threadIdx.x;
    const int lane = tid & 63, w = tid >> 6;
    const int wr = w >> 2, wc = w & 3;
    const int ln15 = lane & 15, kch = lane >> 4;
    const int erow = tid >> 2;
    const int ecol = (((tid & 3) ^ ((tid >> 3) & 3)) << 3);

#define STAGE256(buf, t)                                                      \
    {   const int k0_ = (t) * 32;                                             \
        _Pragma("unroll")                                                     \
        for (int rr = 0; rr < 2; ++rr) {                                      \
            gld_lds16(A  + (size_t)(m0 + rr * 128 + erow) * 1024 + k0_ + ecol,\
                      (short*)As[buf] + rr * 4096 + tid * 8);                 \
            gld_lds16(BT + (size_t)(n0 + rr * 128 + erow) * 1024 + k0_ + ecol,\
                      (short*)Bs[buf] + rr * 4096 + tid * 8);                 \
        } }

#define RF256(Fa, Fb, buf)                                                    \
    {   _Pragma("unroll")                                                     \
        for (int i = 0; i < 8; ++i) {                                         \
            int row = wr * 128 + i * 16 + ln15;                               \
            Fa[i] = *(const short8*)&As[buf][row * 32 + ((kch ^ ((row >> 1) & 3)) << 3)]; \
        }                                                                     \
        _Pragma("unroll")                                                     \
        for (int j = 0; j < 4; ++j) {                                         \
            int row = wc * 64 + j * 16 + ln15;                                \
            Fb[j] = *(const short8*)&Bs[buf][row * 32 + ((kch ^ ((row >> 1) & 3)) << 3)]; \
        } }

#define MM256(Fa, Fb)                                                         \
    {   __builtin_amdgcn_s_setprio(1);                                        \
        _Pragma("unroll")                                                     \
        for (int i = 0; i < 8; ++i)                                           \
            _Pragma("unroll")                                                 \
            for (int j = 0; j < 4; ++j)                                       \
                acc[i][j] = __builtin_amdgcn_mfma_f32_16x16x32_bf16(Fa[i], Fb[j], acc[i][j], 0, 0, 0); \
        __builtin_amdgcn_s_setprio(0); }

#define BODY256(t, Ca, Cb, Na, Nb)                                            \
    {   if ((t) + 3 < 32) STAGE256(((t) + 3) & 3, (t) + 3);                   \
        if ((t) < 29)       asm volatile("s_waitcnt vmcnt(8)" ::: "memory");  \
        else if ((t) == 29) asm volatile("s_waitcnt vmcnt(4)" ::: "memory");  \
        else if ((t) == 30) asm volatile("s_waitcnt vmcnt(0)" ::: "memory");  \
        asm volatile("s_waitcnt lgkmcnt(0)" ::: "memory");                    \
        __builtin_amdgcn_s_barrier();                                         \
        if ((t) < 31) RF256(Na, Nb, ((t) + 1) & 3);                           \
        MM256(Ca, Cb); }

    short8 Xa[8], Xb[4], Ya[8], Yb[4];
    STAGE256(0, 0);
    STAGE256(1, 1);
    STAGE256(2, 2);
    asm volatile("s_waitcnt vmcnt(8)" ::: "memory");
    __builtin_amdgcn_s_barrier();
    RF256(Xa, Xb, 0);
    for (int t2 = 0; t2 < 32; t2 += 2) {
        BODY256(t2, Xa, Xb, Ya, Yb);
        BODY256(t2 + 1, Ya, Yb, Xa, Xb);
    }
#undef STAGE256
#undef RF256
#undef MM256
#undef BODY256
}

// XCD-bijective swizzle (nwg % 8 == 0)
__device__ __forceinline__ int xcd_swz(int lid, int nwg) {
    int q = nwg >> 3;
    return (lid & 7) * q + (lid >> 3);
}

__global__ __launch_bounds__(512, 2) void gemm_bf16(const u16* __restrict__ A,
                                                    const u16* __restrict__ BT,
                                                    float* __restrict__ C) {
    const int lid = blockIdx.y * 4 + blockIdx.x;
    const int sid = xcd_swz(lid, 128);
    const int m0 = (sid >> 2) * 256, n0 = (sid & 3) * 256;
    f32x4 acc[8][4] = {};
    gemm_core256(A, BT, m0, n0, acc);
    const int lane = threadIdx.x & 63, w = threadIdx.x >> 6;
    const int crow0 = m0 + (w >> 2) * 128 + (lane >> 4) * 4;
    const int ccol0 = n0 + (w & 3) * 64 + (lane & 15);
#pragma unroll
    for (int i = 0; i < 8; ++i)
#pragma unroll
        for (int j = 0; j < 4; ++j)
#pragma unroll
            for (int r = 0; r < 4; ++r)
                C[(size_t)(crow0 + i * 16 + r) * 1024 + ccol0 + j * 16] = acc[i][j][r];
}

__global__ __launch_bounds__(512, 2) void gemm_qkv(const u16* __restrict__ A,
                                                   const u16* __restrict__ WT0,
                                                   u16* __restrict__ xq16,
                                                   u16* __restrict__ xk16,
                                                   u16* __restrict__ xv16) {
    const int lid = blockIdx.y * 12 + blockIdx.x;
    const int sid = xcd_swz(lid, 384);
    const int lbx = sid % 12;
    const int which = lbx >> 2;
    const int n0 = (lbx & 3) * 256;
    const int m0 = (sid / 12) * 256;
    const u16* BT = WT0 + (size_t)which * 1048576;
    f32x4 acc[8][4] = {};
    gemm_core256(A, BT, m0, n0, acc);
    const int lane = threadIdx.x & 63, w = threadIdx.x >> 6;
    const int crow0 = m0 + (w >> 2) * 128 + (lane >> 4) * 4;
    const int ccol0 = n0 + (w & 3) * 64 + (lane & 15);
    u16* C16 = (which == 0) ? xq16 : (which == 1) ? xk16 : xv16;
#pragma unroll
    for (int i = 0; i < 8; ++i)
#pragma unroll
        for (int j = 0; j < 4; ++j)
#pragma unroll
            for (int r = 0; r < 4; ++r)
                C16[(size_t)(crow0 + i * 16 + r) * 1024 + ccol0 + j * 16] = f2bf(acc[i][j][r]);
}

// ---------------------------------------------------------------------------
// beta = sigmoid(x @ Wb) stored [B,H,L]; reads bf16 x
// ---------------------------------------------------------------------------
__global__ __launch_bounds__(256) void beta_k(const u16* __restrict__ X16,
                                              const float* __restrict__ Wb,
                                              float* __restrict__ beta) {
    int idx = blockIdx.x * 256 + threadIdx.x;
    int row = idx >> 4, h = idx & 15;
    const u16* xr = X16 + (size_t)row * DD;
    float s = 0.f;
    for (int k8 = 0; k8 < DD; k8 += 8) {
        short8 xv = *(const short8*)&xr[k8];
#pragma unroll
        for (int e = 0; e < 8; ++e)
            s += bf2f((u16)xv[e]) * Wb[(k8 + e) * HH + h];
    }
    float bv = 1.f / (1.f + expf(-s));
    int b = row >> 12, l = row & (LL - 1);
    beta[((size_t)b * HH + h) * LL + l] = bv;
}

// ---------------------------------------------------------------------------
// 3x fused conv, all bf16: which 0=q(norm) 1=k(norm) 2=v
// ---------------------------------------------------------------------------
__global__ __launch_bounds__(256) void conv3_k(const u16* __restrict__ xq16,
                                               const u16* __restrict__ xk16,
                                               const u16* __restrict__ xv16,
                                               const float* __restrict__ cwq,
                                               const float* __restrict__ cwk,
                                               const float* __restrict__ cwv,
                                               u16* __restrict__ q16,
                                               u16* __restrict__ k16,
                                               u16* __restrict__ v16) {
    const int which = blockIdx.z;
    const float* cw = (which == 0) ? cwq : (which == 1) ? cwk : cwv;
    const int l0 = blockIdx.x * 16, b = blockIdx.y;
    const int tid = threadIdx.x;
    const int d0 = tid * 4;
    const float4 w0 = *(const float4*)&cw[(d0 + 0) * 4];
    const float4 w1 = *(const float4*)&cw[(d0 + 1) * 4];
    const float4 w2 = *(const float4*)&cw[(d0 + 2) * 4];
    const float4 w3 = *(const float4*)&cw[(d0 + 3) * 4];
    const int h = d0 >> 6, hd = d0 & 63;
    const u16* Xb = ((which == 0) ? xq16 : (which == 1) ? xk16 : xv16) + (size_t)b * LL * DD;
    u16* O16 = (which == 0) ? q16 : (which == 1) ? k16 : v16;
    float4 xm3 = make_float4(0, 0, 0, 0), xm2 = xm3, xm1 = xm3;
    if (l0 > 0) {
        xm3 = ld_bf4(&Xb[(size_t)(l0 - 3) * DD + d0]);
        xm2 = ld_bf4(&Xb[(size_t)(l0 - 2) * DD + d0]);
        xm1 = ld_bf4(&Xb[(size_t)(l0 - 1) * DD + d0]);
    }
#pragma unroll
    for (int t = 0; t < 16; ++t) {
        const int l = l0 + t;
        float4 xc = ld_bf4(&Xb[(size_t)l * DD + d0]);
        float a0 = xm3.x * w0.x + xm2.x * w0.y + xm1.x * w0.z + xc.x * w0.w;
        float a1 = xm3.y * w1.x + xm2.y * w1.y + xm1.y * w1.z + xc.y * w1.w;
        float a2 = xm3.z * w2.x + xm2.z * w2.y + xm1.z * w2.z + xc.z * w2.w;
        float a3 = xm3.w * w3.x + xm2.w * w3.y + xm1.w * w3.z + xc.w * w3.w;
        a0 = a0 / (1.f + expf(-a0));
        a1 = a1 / (1.f + expf(-a1));
        a2 = a2 / (1.f + expf(-a2));
        a3 = a3 / (1.f + expf(-a3));
        if (which < 2) {
            float s = a0 * a0 + a1 * a1 + a2 * a2 + a3 * a3;
            s += __shfl_xor(s, 1);
            s += __shfl_xor(s, 2);
            s += __shfl_xor(s, 4);
            s += __shfl_xor(s, 8);
            float sc = rsqrtf(s);
            a0 *= sc; a1 *= sc; a2 *= sc; a3 *= sc;
        }
        uint2 o;
        o.x = (unsigned)f2bf(a0) | ((unsigned)f2bf(a1) << 16);
        o.y = (unsigned)f2bf(a2) | ((unsigned)f2bf(a3) << 16);
        *(uint2*)&O16[(((size_t)b * HH + h) * LL + l) * 64 + hd] = o;
        xm3 = xm2; xm2 = xm1; xm1 = xc;
    }
}

// ---------------------------------------------------------------------------
// Phase A: K,V exact bf16. W,U plain bf16 out. P,B plain fp32 out.
// ---------------------------------------------------------------------------
__global__ __launch_bounds__(256) void phaseA6(const u16* __restrict__ kg16,
                                               const u16* __restrict__ vg16,
                                               const float* __restrict__ betag,
                                               u16* __restrict__ Wg16,
                                               u16* __restrict__ UgT16,
                                               float* __restrict__ Pall,
                                               float* __restrict__ BallT) {
    __shared__ __align__(16) char pool[65536];
    u16* Kh   = (u16*)pool;              // 0-8K; later WTh
    u16* KTh  = (u16*)(pool + 8192);     // 8-16K (persists)
    float* At = (float*)(pool + 16384);  // 16-32K; later WTl/UTh
    float* WU = (float*)(pool + 32768);  // 32-64K; later scr/scrP
    u16* WTh  = (u16*)pool;
    u16* WTl  = (u16*)(pool + 16384);
    u16* UTh  = (u16*)(pool + 24576);
    float* scr  = (float*)(pool + 32768);  // B scratch (32-48K)
    float* scrP = (float*)(pool + 49152);  // P scratch (48-64K)

    const int c = blockIdx.x, bh = blockIdx.y;
    const int tid = threadIdx.x, lane = tid & 63, w = tid >> 6;
    const int g = lane >> 4, ln = lane & 15;
    const int t0 = (tid >> 4) * 4, d4 = (tid & 15) * 4;
    const size_t base = ((size_t)bh * LL + (size_t)c * 64) * 64;
    const size_t obase = ((size_t)bh * NC + c) * 4096;
    const float* bet = betag + (size_t)bh * LL + (size_t)c * 64;

    // 1a. K (bf16) -> Kh swizzled
    g_to_ls_b(kg16 + base, Kh, tid);
    // 1b. K^T -> KTh (global re-read 4x4, packed transposed stores)
    {
        u16 kv[4][4];
#pragma unroll
        for (int i = 0; i < 4; ++i) {
            uint2 v = *(const uint2*)&kg16[base + (size_t)(t0 + i) * 64 + d4];
            kv[i][0] = (u16)v.x; kv[i][1] = (u16)(v.x >> 16);
            kv[i][2] = (u16)v.y; kv[i][3] = (u16)(v.y >> 16);
        }
#pragma unroll
        for (int j = 0; j < 4; ++j) {
            uint2 hv;
            hv.x = (unsigned)kv[0][j] | ((unsigned)kv[1][j] << 16);
            hv.y = (unsigned)kv[2][j] | ((unsigned)kv[3][j] << 16);
            *(uint2*)&KTh[swze(d4 + j, t0)] = hv;
        }
    }
    __syncthreads();
    // 2. Gram A = strict_tril(beta * K K^T)
    {
        f32x4 acc[4] = {};
        mm64_bb(Kh, Kh, acc, w, lane);
#pragma unroll
        for (int r = 0; r < 4; ++r) {
            int t = w * 16 + g * 4 + r;
            float bt = bet[t];
#pragma unroll
            for (int j = 0; j < 4; ++j) {
                int s = j * 16 + ln;
                At[t * 64 + s] = (s < t) ? bt * acc[j][r] : 0.f;
            }
        }
    }
    // 3. RHS: WU[t][j] = beta_t * (j<64 ? K[t][j] : V[t][j-64])
#pragma unroll
    for (int p = 0; p < 8; ++p) {
        int flat = p * 1024 + tid * 4;
        int t = flat >> 7, j = flat & 127;
        float bt = bet[t];
        float4 src;
        if (j < 64) src = ld_bf4(&Kh[swze(t, j)]);
        else        src = ld_bf4(&vg16[base + (size_t)t * 64 + (j - 64)]);
        src.x *= bt; src.y *= bt; src.z *= bt; src.w *= bt;
        *(float4*)&WU[t * 128 + j] = src;
    }
    __syncthreads();
    // 4. blocked forward substitution (panels of 16)
#pragma unroll
    for (int pb = 0; pb < 4; ++pb) {
        const int r0 = pb * 16;
        if (pb > 0) {
            const int col = tid & 127;
            const int rbase = r0 + (tid >> 7) * 8;
            float acc8[8] = {};
            for (int r = 0; r < r0; r += 4) {
                float u0 = WU[(r + 0) * 128 + col], u1 = WU[(r + 1) * 128 + col];
                float u2 = WU[(r + 2) * 128 + col], u3 = WU[(r + 3) * 128 + col];
#pragma unroll
                for (int i = 0; i < 8; ++i) {
                    float4 a4 = *(const float4*)&At[(rbase + i) * 64 + r];
                    acc8[i] += a4.x * u0 + a4.y * u1 + a4.z * u2 + a4.w * u3;
                }
            }
#pragma unroll
            for (int i = 0; i < 8; ++i) WU[(rbase + i) * 128 + col] -= acc8[i];
            __syncthreads();
        }
        if (tid < 128) {
            const int col = tid;
            float wv[16];
            wv[0] = WU[r0 * 128 + col];
#pragma unroll
            for (int t = 1; t < 16; ++t) {
                float a = WU[(r0 + t) * 128 + col];
#pragma unroll
                for (int r = 0; r < t; ++r) a -= At[(r0 + t) * 64 + r0 + r] * wv[r];
                wv[t] = a;
            }
#pragma unroll
            for (int t = 1; t < 16; ++t) WU[(r0 + t) * 128 + col] = wv[t];
        }
        __syncthreads();
    }
    // 5a. Wg16 global write (plain bf16, coalesced uint2)
#pragma unroll
    for (int p = 0; p < 4; ++p) {
        int flat = p * 1024 + tid * 4;
        int t = flat >> 6, j = flat & 63;
        float4 v = *(const float4*)&WU[t * 128 + j];
        uint2 o;
        o.x = (unsigned)f2bf(v.x) | ((unsigned)f2bf(v.y) << 16);
        o.y = (unsigned)f2bf(v.z) | ((unsigned)f2bf(v.w) << 16);
        *(uint2*)&Wg16[obase + flat] = o;
    }
    // 5b. W^T split build + U^T plain-bf16 build (transposed packed stores)
    {
        u16 h4[4][4], l4[4][4];
#pragma unroll
        for (int i = 0; i < 4; ++i) {
            float4 v = *(const float4*)&WU[(t0 + i) * 128 + d4];
            split2(v.x, h4[i][0], l4[i][0]); split2(v.y, h4[i][1], l4[i][1]);
            split2(v.z, h4[i][2], l4[i][2]); split2(v.w, h4[i][3], l4[i][3]);
        }
#pragma unroll
        for (int j = 0; j < 4; ++j) {
            uint2 hv, lv;
            hv.x = (unsigned)h4[0][j] | ((unsigned)h4[1][j] << 16);
            hv.y = (unsigned)h4[2][j] | ((unsigned)h4[3][j] << 16);
            lv.x = (unsigned)l4[0][j] | ((unsigned)l4[1][j] << 16);
            lv.y = (unsigned)l4[2][j] | ((unsigned)l4[3][j] << 16);
            *(uint2*)&WTh[swze(d4 + j, t0)] = hv;
            *(uint2*)&WTl[swze(d4 + j, t0)] = lv;
        }
#pragma unroll
        for (int i = 0; i < 4; ++i) {
            float4 v = *(const float4*)&WU[(t0 + i) * 128 + 64 + d4];
            h4[i][0] = f2bf(v.x); h4[i][1] = f2bf(v.y);
            h4[i][2] = f2bf(v.z); h4[i][3] = f2bf(v.w);
        }
#pragma unroll
        for (int j = 0; j < 4; ++j) {
            uint2 hv;
            hv.x = (unsigned)h4[0][j] | ((unsigned)h4[1][j] << 16);
            hv.y = (unsigned)h4[2][j] | ((unsigned)h4[3][j] << 16);
            *(uint2*)&UTh[swze(d4 + j, t0)] = hv;
        }
    }
    __syncthreads();
    // 6. UgT16 global write (plain bf16 from UTh, coalesced short8)
#pragma unroll
    for (int p = 0; p < 2; ++p) {
        int flat = p * 2048 + tid * 8;
        int n = flat >> 6, tt = flat & 63;
        *(short8*)&UgT16[obase + flat] = *(const short8*)&UTh[swze(n, tt)];
    }
    // 7. P = I - K^T W (split W); B = K^T U (U exact, 1-term)
    f32x4 aP[4] = {}, aB[4] = {};
    mm64_ab(KTh, WTh, WTl, aP, w, lane);
    mm64_bb(KTh, UTh, aB, w, lane);
#pragma unroll
    for (int j = 0; j < 4; ++j)
#pragma unroll
        for (int r = 0; r < 4; ++r) {
            int row = w * 16 + g * 4 + r, col = j * 16 + ln;
            scrP[swz(row, col)] = ((row == col) ? 1.f : 0.f) - aP[j][r];
            scr[swz(row, col)] = aB[j][r];
        }
    __syncthreads();
    // 8. Pall (plain) + BallT (transposed), both coalesced fp32 float4 streams
#pragma unroll
    for (int p = 0; p < 4; ++p) {
        int flat = p * 1024 + tid * 4;
        int rr = flat >> 6, cc = flat & 63;
        float4 op = make_float4(scrP[swz(rr, cc + 0)], scrP[swz(rr, cc + 1)],
                                scrP[swz(rr, cc + 2)], scrP[swz(rr, cc + 3)]);
        *(float4*)&Pall[obase + flat] = op;
        float4 ob4 = make_float4(scr[swz(cc + 0, rr)], scr[swz(cc + 1, rr)],
                                 scr[swz(cc + 2, rr)], scr[swz(cc + 3, rr)]);
        *(float4*)&BallT[obase + flat] = ob4;
    }
}

// ---------------------------------------------------------------------------
// compose4: fp32 I/O + T14 register prefetch of next P tile.
// ---------------------------------------------------------------------------
__global__ __launch_bounds__(256) void compose4(const float* __restrict__ Pall,
                                                const float* __restrict__ BallT,
                                                float* __restrict__ Pg,
                                                float* __restrict__ BgT) {
    __shared__ __align__(16) char pool[81920];
    u16* Ph = (u16*)pool;
    u16* Pl = (u16*)(pool + 8192);
    u16* Bh = (u16*)(pool + 16384);
    u16* Bl = (u16*)(pool + 24576);
    u16* nh = (u16*)(pool + 32768);
    u16* nl = (u16*)(pool + 40960);
    float* scr = (float*)(pool + 49152);
    const int g = blockIdx.x, bh = blockIdx.y;
    const int tid = threadIdx.x, lane = tid & 63, w = tid >> 6;
    const int gi = lane >> 4, ln = lane & 15;
    const size_t base0 = ((size_t)bh * NC + (size_t)g * GS) * 4096;
    f32x4 mP[4], mB[4];
#pragma unroll
    for (int p = 0; p < 4; ++p) {
        int flat = p * 1024 + tid * 4;
        int r = flat >> 6, c4 = flat & 63;
        *(float4*)&scr[swz(r, c4)] = *(const float4*)&Pall[base0 + flat];
    }
    g_to_frag(BallT + base0, mB, w, lane);
    __syncthreads();
#pragma unroll
    for (int j = 0; j < 4; ++j)
#pragma unroll
        for (int r = 0; r < 4; ++r) {
            int row = w * 16 + gi * 4 + r, col = j * 16 + ln;
            mP[j][r] = scr[swz(col, row)];
        }
    float4 pf[4];
    pload_f(pf, Pall + base0 + 4096, tid);
    for (int s = 1; s < GS; ++s) {
        __syncthreads();
        frag_to_ls(mP, Ph, Pl, w, lane);
        frag_to_ls(mB, Bh, Bl, w, lane);
        pstore_ls_f(pf, nh, nl, tid);
        __syncthreads();
        if (s < GS - 1) pload_f(pf, Pall + base0 + (size_t)(s + 1) * 4096, tid);
        f32x4 aP[4] = {}, aB[4] = {};
        mm64(Ph, Pl, nh, nl, aP, w, lane);
        mm64(Bh, Bl, nh, nl, aB, w, lane);
        g_add_frag(BallT + base0 + (size_t)s * 4096, aB, w, lane);
#pragma unroll
        for (int j = 0; j < 4; ++j) { mP[j] = aP[j]; mB[j] = aB[j]; }
    }
    const size_t gbase = ((size_t)bh * GG + g) * 4096;
    frag_to_g(mB, BgT + gbase, w, lane);
    __syncthreads();
#pragma unroll
    for (int j = 0; j < 4; ++j)
#pragma unroll
        for (int r = 0; r < 4; ++r) {
            int row = w * 16 + gi * 4 + r, col = j * 16 + ln;
            scr[swz(row, col)] = mP[j][r];
        }
    __syncthreads();
#pragma unroll
    for (int p = 0; p < 4; ++p) {
        int flat = p * 1024 + tid * 4;
        int a = flat >> 6, b0 = flat & 63;
        float4 o = make_float4(scr[swz(b0 + 0, a)], scr[swz(b0 + 1, a)],
                               scr[swz(b0 + 2, a)], scr[swz(b0 + 3, a)]);
        *(float4*)&Pg[gbase + flat] = o;
    }
}

// ---------------------------------------------------------------------------
// scanG4: fp32 I/O.
// ---------------------------------------------------------------------------
__global__ __launch_bounds__(256) void scanG4(const float* __restrict__ Pg,
                                              const float* __restrict__ BgT,
                                              float* __restrict__ SallT) {
    __shared__ __align__(16) char pool[32768];
    u16* Sh = (u16*)pool;
    u16* Sl = (u16*)(pool + 8192);
    u16* nh = (u16*)(pool + 16384);
    u16* nl = (u16*)(pool + 24576);
    const int bh = blockIdx.x;
    const int tid = threadIdx.x, lane = tid & 63, w = tid >> 6;
    f32x4 mS[4] = {};
    for (int g = 0; g < GG; ++g) {
        const size_t sbase = ((size_t)bh * NC + (size_t)g * GS) * 4096;
        frag_to_g(mS, SallT + sbase, w, lane);
        if (g == GG - 1) break;
        __syncthreads();
        frag_to_ls(mS, Sh, Sl, w, lane);
        g_to_ls(Pg + ((size_t)bh * GG + g) * 4096, nh, nl, tid);
        __syncthreads();
        f32x4 a[4] = {};
        mm64(Sh, Sl, nh, nl, a, w, lane);
        g_add_frag(BgT + ((size_t)bh * GG + g) * 4096, a, w, lane);
#pragma unroll
        for (int j = 0; j < 4; ++j) mS[j] = a[j];
    }
}

// ---------------------------------------------------------------------------
// rollout4: fp32 I/O + T14 register prefetch.
// ---------------------------------------------------------------------------
__global__ __launch_bounds__(256) void rollout4(const float* __restrict__ Pall,
                                                const float* __restrict__ BallT,
                                                float* __restrict__ SallT) {
    __shared__ __align__(16) char pool[32768];
    u16* Sh = (u16*)pool;
    u16* Sl = (u16*)(pool + 8192);
    u16* nh = (u16*)(pool + 16384);
    u16* nl = (u16*)(pool + 24576);
    const int g = blockIdx.x, bh = blockIdx.y;
    const int tid = threadIdx.x, lane = tid & 63, w = tid >> 6;
    const size_t base0 = ((size_t)bh * NC + (size_t)g * GS) * 4096;
    f32x4 mS[4];
    g_to_frag(SallT + base0, mS, w, lane);
    float4 pf[4];
    pload_f(pf, Pall + base0, tid);
    for (int j = 1; j < GS; ++j) {
        __syncthreads();
        frag_to_ls(mS, Sh, Sl, w, lane);
        pstore_ls_f(pf, nh, nl, tid);
        __syncthreads();
        if (j < GS - 1) pload_f(pf, Pall + base0 + (size_t)j * 4096, tid);
        f32x4 a[4] = {};
        mm64(Sh, Sl, nh, nl, a, w, lane);
        g_add_frag(BallT + base0 + (size_t)(j - 1) * 4096, a, w, lane);
#pragma unroll
        for (int jj = 0; jj < 4; ++jj) mS[jj] = a[jj];
        frag_to_g(mS, SallT + base0 + (size_t)j * 4096, w, lane);
    }
}

// ---------------------------------------------------------------------------
// phaseO6: W,U plain bf16 (U staged to LDS); S fp32; Q,K exact bf16.
// M=causal(QK^T); Delta^T = U^T - (WS)^T; O = QS + M*Delta; fused RMSNorm.
// ---------------------------------------------------------------------------
__global__ __launch_bounds__(256) void phaseO6(const u16* __restrict__ Wg16,
                                               const u16* __restrict__ UgT16,
                                               const u16* __restrict__ qg16,
                                               const u16* __restrict__ kg16,
                                               const float* __restrict__ SallT,
                                               const float* __restrict__ nw,
                                               u16* __restrict__ ob) {
    __shared__ __align__(16) char pool[65536];
    u16* Qh = (u16*)pool;               // 8K
    u16* Kh = (u16*)(pool + 8192);      // 8K; later Dh
    u16* Wh = (u16*)(pool + 16384);     // 8K; later Mh
    u16* Wl = (u16*)(pool + 24576);     // 8K; Ml
    u16* Sh = (u16*)(pool + 32768);
    u16* Sl = (u16*)(pool + 40960);
    u16* Dl = (u16*)(pool + 49152);     // 8K
    u16* Uh = (u16*)(pool + 57344);     // 8K staged U^T
    u16* Dh = Kh;
    u16* Mh = Wh; u16* Ml = Wl;
    const int c = blockIdx.x, bh = blockIdx.y;
    const int b = bh >> 4, h = bh & 15;
    const int tid = threadIdx.x, lane = tid & 63, w = tid >> 6;
    const int gi = lane >> 4, ln = lane & 15;
    const size_t tbase = ((size_t)bh * NC + c) * 4096;
    const size_t qkbase = ((size_t)bh * LL + (size_t)c * 64) * 64;
    g_to_ls_b(qg16 + qkbase, Qh, tid);
    g_to_ls_b(kg16 + qkbase, Kh, tid);
    g_to_ls_b(Wg16 + tbase, Wh, tid);
    g_to_ls_b(UgT16 + tbase, Uh, tid);
    g_to_ls(SallT + tbase, Sh, Sl, tid);
    __syncthreads();
    f32x4 aM[4] = {}, aD[4] = {};
    mm64_bb(Qh, Kh, aM, w, lane);        // Q K^T
    mm64_sb(Sh, Sl, Wh, aD, w, lane);    // (W S)^T   (S split, W exact)
    __syncthreads();                     // all K/W reads done
#pragma unroll
    for (int j = 0; j < 4; ++j)
#pragma unroll
        for (int r = 0; r < 4; ++r) {
            int row = w * 16 + gi * 4 + r, col = j * 16 + ln;
            float mv = (col <= row) ? aM[j][r] : 0.f;
            u16 mh_, ml_; split2(mv, mh_, ml_);
            Mh[swze(row, col)] = mh_;
            Ml[swze(row, col)] = ml_;
            float dv = bf2f(Uh[swze(row, col)]) - aD[j][r];
            u16 dh_, dl_; split2(dv, dh_, dl_);
            Dh[swze(row, col)] = dh_;
            Dl[swze(row, col)] = dl_;
        }
    __syncthreads();
    f32x4 aO[4] = {};
    mm64_ab(Qh, Sh, Sl, aO, w, lane);    // Q S
    mm64(Mh, Ml, Dh, Dl, aO, w, lane);   // + M Delta
    float nwv[4];
#pragma unroll
    for (int j = 0; j < 4; ++j) nwv[j] = nw[j * 16 + ln];
#pragma unroll
    for (int r = 0; r < 4; ++r) {
        float ss = 0.f;
#pragma unroll
        for (int j = 0; j < 4; ++j) ss += aO[j][r] * aO[j][r];
        ss += __shfl_xor(ss, 1);
        ss += __shfl_xor(ss, 2);
        ss += __shfl_xor(ss, 4);
        ss += __shfl_xor(ss, 8);
        float rms = rsqrtf(ss * (1.f / 64.f) + 1e-5f);
        int row = w * 16 + gi * 4 + r;
        size_t orow = ((size_t)b * LL + (size_t)c * 64 + row) * DD + (size_t)h * 64;
#pragma unroll
        for (int j = 0; j < 4; ++j)
            ob[orow + j * 16 + ln] = f2bf(aO[j][r] * rms * nwv[j]);
    }
}

// ---------------------------------------------------------------------------
extern "C" void kernel_launch(void* const* d_in, const int* in_sizes, int n_in,
                              void* d_out, int out_size, void* d_ws, size_t ws_size,
                              hipStream_t stream) {
    const float* x  = (const float*)d_in[0];
    const float* Wq = (const float*)d_in[1];
    const float* Wk = (const float*)d_in[2];
    const float* Wv = (const float*)d_in[3];
    const float* Wb = (const float*)d_in[4];
    const float* cq = (const float*)d_in[5];
    const float* ck = (const float*)d_in[6];
    const float* cv = (const float*)d_in[7];
    const float* nw = (const float*)d_in[8];
    const float* Wo = (const float*)d_in[9];
    float* out = (float*)d_out;
    float* ws = (float*)d_ws;

    const size_t SZ = (size_t)BB * LL * DD;   // 8388608
    u16* xv16    = (u16*)ws;        // gemm v out; slab reused as Pall
    u16* v16     = (u16*)(ws + SZ); // conv v out; slab reused as ob
    u16* Wg16    = (u16*)(ws + 2 * SZ);       // plain bf16 W tiles
    u16* UgT16   = (u16*)(ws + 2 * SZ) + SZ;  // plain bf16 U^T tiles
    float* SallT = ws + 4 * SZ;
    u16* xb   = (u16*)(ws + 5 * SZ);          // x bf16; dead after conv/beta
    u16* q16  = xb;                           // conv q out (reuses xb)
    u16* xq16 = (u16*)(ws + 5 * SZ) + SZ;
    u16* xk16 = (u16*)(ws + 5 * SZ) + 2 * SZ;
    u16* k16  = (u16*)(ws + 5 * SZ) + 3 * SZ;
    float* beta = ws + 7 * SZ;                        // 131072 floats
    u16* wqT  = (u16*)(beta + (size_t)BH * LL);       // 4M u16 (q,k,v,o)
    float* Pg  = (float*)(wqT + (size_t)4 * 1048576); // 1M floats
    float* BgT = Pg + 1048576;                        // 1M floats

    float* Pall  = ws;        // overwrites xv16 (dead after conv3)
    float* BallT = out;       // d_out as scratch; fully overwritten by final GEMM
    u16* ob   = (u16*)(ws + SZ);   // overwrites v16 (dead after phaseA6)
    u16* woT  = wqT + (size_t)3 * 1048576;

    dim3 blk(256);

    prep_k<<<dim3(8192), blk, 0, stream>>>(x, xb, Wq, Wk, Wv, Wo, wqT);
    gemm_qkv<<<dim3(12, 32), dim3(512), 0, stream>>>(xb, wqT, xq16, xk16, xv16);
    beta_k<<<dim3(512), blk, 0, stream>>>(xb, Wb, beta);
    conv3_k<<<dim3(LL / 16, BB, 3), blk, 0, stream>>>(xq16, xk16, xv16, cq, ck, cv, q16, k16, v16);
    phaseA6<<<dim3(NC, BH), blk, 0, stream>>>(k16, v16, beta, Wg16, UgT16, Pall, BallT);
    compose4<<<dim3(GG, BH), blk, 0, stream>>>(Pall, BallT, Pg, BgT);
    scanG4<<<dim3(BH), blk, 0, stream>>>(Pg, BgT, SallT);
    rollout4<<<dim3(GG, BH), blk, 0, stream>>>(Pall, BallT, SallT);
    phaseO6<<<dim3(NC, BH), blk, 0, stream>>>(Wg16, UgT16, q16, k16, SallT, nw, ob);
    gemm_bf16<<<dim3(4, 32), dim3(512), 0, stream>>>(ob, woT, out);
}

// Round 19
// 311.832 us; speedup vs baseline: 1.0836x; 1.0254x over previous
//
#include <hip/hip_runtime.h>
#include <hip/hip_bf16.h>
#include <math.h>

#define BB 2
#define LL 4096
#define DD 1024
#define HH 16
#define HDIM 64
#define CC 64
#define NC 64   // LL/CC
#define BH 32   // BB*HH
#define GG 8    // chunk groups
#define GS 8    // chunks per group

typedef __attribute__((ext_vector_type(8))) short short8;
typedef __attribute__((ext_vector_type(4))) float f32x4;
typedef unsigned short u16;
typedef unsigned int u32;

__device__ __forceinline__ u16 f2bf(float f) {
    unsigned int u = __float_as_uint(f);
    unsigned int r = (u + 0x7fffu + ((u >> 16) & 1u)) >> 16;
    return (u16)r;
}
__device__ __forceinline__ float bf2f(u16 h) {
    return __uint_as_float((unsigned)h << 16);
}
__device__ __forceinline__ void split2(float x, u16& h, u16& l) {
    h = f2bf(x);
    l = f2bf(x - bf2f(h));
}
__device__ __forceinline__ float4 ld_bf4(const u16* p) {
    uint2 v = *(const uint2*)p;
    return make_float4(bf2f((u16)v.x), bf2f((u16)(v.x >> 16)),
                       bf2f((u16)v.y), bf2f((u16)(v.y >> 16)));
}

__device__ __forceinline__ void gld_lds16(const void* g, void* l) {
    __builtin_amdgcn_global_load_lds(
        (const __attribute__((address_space(1))) void*)g,
        (__attribute__((address_space(3))) void*)l, 16, 0, 0);
}

// fp32 [64][64] tile swizzle (4-elem chunks XOR'd by row>>2)
__device__ __forceinline__ int swz(int r, int c) {
    return (r << 6) + ((((c >> 2) ^ (r >> 2)) & 15) << 2) + (c & 3);
}
// bf16 [64][64] tile swizzle (reads + stride-4 transposed writes both 2-way)
__device__ __forceinline__ int swze(int r, int c) {
    return (r << 6) + (c ^ (((r ^ (r >> 3)) & 7) << 3));
}

// ---------------------------------------------------------------------------
// mm64 variants: C[a][b] += sum_k A[a][k]*B[b][k]; A,B in swizzled LDS tiles.
// ---------------------------------------------------------------------------
__device__ __forceinline__ void mm64(const u16* __restrict__ Ah, const u16* __restrict__ Al,
                                     const u16* __restrict__ Bh, const u16* __restrict__ Bl,
                                     f32x4* acc, int w, int lane) {
    const int ln = lane & 15, kg = (lane >> 4) * 8;
#pragma unroll
    for (int kb = 0; kb < 2; ++kb) {
        const int k0 = kb * 32 + kg;
        short8 ah = *(const short8*)&Ah[swze(w * 16 + ln, k0)];
        short8 al = *(const short8*)&Al[swze(w * 16 + ln, k0)];
#pragma unroll
        for (int j = 0; j < 4; ++j) {
            short8 bh = *(const short8*)&Bh[swze(j * 16 + ln, k0)];
            short8 bl = *(const short8*)&Bl[swze(j * 16 + ln, k0)];
            acc[j] = __builtin_amdgcn_mfma_f32_16x16x32_bf16(ah, bh, acc[j], 0, 0, 0);
            acc[j] = __builtin_amdgcn_mfma_f32_16x16x32_bf16(ah, bl, acc[j], 0, 0, 0);
            acc[j] = __builtin_amdgcn_mfma_f32_16x16x32_bf16(al, bh, acc[j], 0, 0, 0);
        }
    }
}
// both operands exact bf16
__device__ __forceinline__ void mm64_bb(const u16* __restrict__ Ah,
                                        const u16* __restrict__ Bh,
                                        f32x4* acc, int w, int lane) {
    const int ln = lane & 15, kg = (lane >> 4) * 8;
#pragma unroll
    for (int kb = 0; kb < 2; ++kb) {
        const int k0 = kb * 32 + kg;
        short8 ah = *(const short8*)&Ah[swze(w * 16 + ln, k0)];
#pragma unroll
        for (int j = 0; j < 4; ++j) {
            short8 bh = *(const short8*)&Bh[swze(j * 16 + ln, k0)];
            acc[j] = __builtin_amdgcn_mfma_f32_16x16x32_bf16(ah, bh, acc[j], 0, 0, 0);
        }
    }
}
// A exact bf16, B split
__device__ __forceinline__ void mm64_ab(const u16* __restrict__ Ah,
                                        const u16* __restrict__ Bh, const u16* __restrict__ Bl,
                                        f32x4* acc, int w, int lane) {
    const int ln = lane & 15, kg = (lane >> 4) * 8;
#pragma unroll
    for (int kb = 0; kb < 2; ++kb) {
        const int k0 = kb * 32 + kg;
        short8 ah = *(const short8*)&Ah[swze(w * 16 + ln, k0)];
#pragma unroll
        for (int j = 0; j < 4; ++j) {
            short8 bh = *(const short8*)&Bh[swze(j * 16 + ln, k0)];
            short8 bl = *(const short8*)&Bl[swze(j * 16 + ln, k0)];
            acc[j] = __builtin_amdgcn_mfma_f32_16x16x32_bf16(ah, bh, acc[j], 0, 0, 0);
            acc[j] = __builtin_amdgcn_mfma_f32_16x16x32_bf16(ah, bl, acc[j], 0, 0, 0);
        }
    }
}
// A split, B exact bf16
__device__ __forceinline__ void mm64_sb(const u16* __restrict__ Ah, const u16* __restrict__ Al,
                                        const u16* __restrict__ Bh,
                                        f32x4* acc, int w, int lane) {
    const int ln = lane & 15, kg = (lane >> 4) * 8;
#pragma unroll
    for (int kb = 0; kb < 2; ++kb) {
        const int k0 = kb * 32 + kg;
        short8 ah = *(const short8*)&Ah[swze(w * 16 + ln, k0)];
        short8 al = *(const short8*)&Al[swze(w * 16 + ln, k0)];
#pragma unroll
        for (int j = 0; j < 4; ++j) {
            short8 bh = *(const short8*)&Bh[swze(j * 16 + ln, k0)];
            acc[j] = __builtin_amdgcn_mfma_f32_16x16x32_bf16(ah, bh, acc[j], 0, 0, 0);
            acc[j] = __builtin_amdgcn_mfma_f32_16x16x32_bf16(al, bh, acc[j], 0, 0, 0);
        }
    }
}

// global bf16 [64][64] -> swizzled LDS copy
__device__ __forceinline__ void g_to_ls_b(const u16* __restrict__ G16, u16* Ah, int tid) {
#pragma unroll
    for (int p = 0; p < 2; ++p) {
        int flat = p * 2048 + tid * 8;
        int r = flat >> 6, c = flat & 63;
        *(short8*)&Ah[swze(r, c)] = *(const short8*)&G16[flat];
    }
}

// global fp32 [64][64] -> hi/lo bf16 LDS (split at consumer)
__device__ __forceinline__ void g_to_ls(const float* __restrict__ G, u16* Ah, u16* Al, int tid) {
#pragma unroll
    for (int p = 0; p < 4; ++p) {
        int flat = p * 1024 + tid * 4;
        int r = flat >> 6, c = flat & 63;
        float4 v = *(const float4*)&G[flat];
        u16 h0, l0, h1, l1, h2, l2, h3, l3;
        split2(v.x, h0, l0); split2(v.y, h1, l1);
        split2(v.z, h2, l2); split2(v.w, h3, l3);
        int idx = swze(r, c);
        uint2 hv, lv;
        hv.x = (unsigned)h0 | ((unsigned)h1 << 16); hv.y = (unsigned)h2 | ((unsigned)h3 << 16);
        lv.x = (unsigned)l0 | ((unsigned)l1 << 16); lv.y = (unsigned)l2 | ((unsigned)l3 << 16);
        *(uint2*)&Ah[idx] = hv;
        *(uint2*)&Al[idx] = lv;
    }
}

// fp32 global: register prefetch + split LDS store (T14)
__device__ __forceinline__ void pload_f(float4 pf[4], const float* __restrict__ G, int tid) {
    pf[0] = *(const float4*)&G[tid * 8];
    pf[1] = *(const float4*)&G[tid * 8 + 4];
    pf[2] = *(const float4*)&G[2048 + tid * 8];
    pf[3] = *(const float4*)&G[2048 + tid * 8 + 4];
}
__device__ __forceinline__ void pstore_ls_f(const float4 pf[4], u16* Ah, u16* Al, int tid) {
#pragma unroll
    for (int p = 0; p < 2; ++p) {
        int flat = p * 2048 + tid * 8;
        int r = flat >> 6, c = flat & 63;
        float4 a = pf[2 * p], b = pf[2 * p + 1];
        u16 h[8], l[8];
        split2(a.x, h[0], l[0]); split2(a.y, h[1], l[1]);
        split2(a.z, h[2], l[2]); split2(a.w, h[3], l[3]);
        split2(b.x, h[4], l[4]); split2(b.y, h[5], l[5]);
        split2(b.z, h[6], l[6]); split2(b.w, h[7], l[7]);
        short8 hi, lo;
#pragma unroll
        for (int e = 0; e < 8; ++e) { hi[e] = (short)h[e]; lo[e] = (short)l[e]; }
        *(short8*)&Ah[swze(r, c)] = hi;
        *(short8*)&Al[swze(r, c)] = lo;
    }
}

// register frag -> hi/lo bf16 LDS
__device__ __forceinline__ void frag_to_ls(const f32x4* acc, u16* Ah, u16* Al, int w, int lane) {
    const int g = lane >> 4, ln = lane & 15;
#pragma unroll
    for (int j = 0; j < 4; ++j)
#pragma unroll
        for (int r = 0; r < 4; ++r) {
            int row = w * 16 + g * 4 + r, col = j * 16 + ln;
            u16 h, l; split2(acc[j][r], h, l);
            Ah[swze(row, col)] = h;
            Al[swze(row, col)] = l;
        }
}

// fp32-global frag helpers
__device__ __forceinline__ void g_to_frag(const float* __restrict__ G, f32x4* acc, int w, int lane) {
    const int g = lane >> 4, ln = lane & 15;
#pragma unroll
    for (int j = 0; j < 4; ++j)
#pragma unroll
        for (int r = 0; r < 4; ++r)
            acc[j][r] = G[(w * 16 + g * 4 + r) * 64 + j * 16 + ln];
}
__device__ __forceinline__ void g_add_frag(const float* __restrict__ G, f32x4* acc, int w, int lane) {
    const int g = lane >> 4, ln = lane & 15;
#pragma unroll
    for (int j = 0; j < 4; ++j)
#pragma unroll
        for (int r = 0; r < 4; ++r)
            acc[j][r] += G[(w * 16 + g * 4 + r) * 64 + j * 16 + ln];
}
__device__ __forceinline__ void frag_to_g(const f32x4* acc, float* __restrict__ G, int w, int lane) {
    const int g = lane >> 4, ln = lane & 15;
#pragma unroll
    for (int j = 0; j < 4; ++j)
#pragma unroll
        for (int r = 0; r < 4; ++r)
            G[(w * 16 + g * 4 + r) * 64 + j * 16 + ln] = acc[j][r];
}

// ---------------------------------------------------------------------------
// prep: fused fp32->bf16 cast of x (bid<4096) + 4x W transpose-cast (else)
// ---------------------------------------------------------------------------
__global__ __launch_bounds__(256) void prep_k(const float* __restrict__ in,
                                              u16* __restrict__ out,
                                              const float* __restrict__ W0,
                                              const float* __restrict__ W1,
                                              const float* __restrict__ W2,
                                              const float* __restrict__ W3,
                                              u16* __restrict__ WT0) {
    __shared__ float t[32][33];
    const int bid = blockIdx.x;
    if (bid < 4096) {
        int i = (bid * 256 + threadIdx.x) * 8;
        float4 a = *(const float4*)&in[i];
        float4 b = *(const float4*)&in[i + 4];
        uint4 o;
        o.x = (unsigned)f2bf(a.x) | ((unsigned)f2bf(a.y) << 16);
        o.y = (unsigned)f2bf(a.z) | ((unsigned)f2bf(a.w) << 16);
        o.z = (unsigned)f2bf(b.x) | ((unsigned)f2bf(b.y) << 16);
        o.w = (unsigned)f2bf(b.z) | ((unsigned)f2bf(b.w) << 16);
        *(uint4*)&out[i] = o;
        return;
    }
    const int t2 = bid - 4096;
    const int which = t2 >> 10, rem = t2 & 1023;
    const int bx = (rem & 31) * 32, by = (rem >> 5) * 32;
    const float* W = (which == 0) ? W0 : (which == 1) ? W1 : (which == 2) ? W2 : W3;
    u16* WT = WT0 + (size_t)which * 1048576;
#pragma unroll
    for (int p = 0; p < 4; ++p) {
        int idx = p * 256 + threadIdx.x;
        int r = idx >> 5, cc = idx & 31;
        t[r][cc] = W[(size_t)(by + r) * 1024 + bx + cc];
    }
    __syncthreads();
#pragma unroll
    for (int p = 0; p < 4; ++p) {
        int idx = p * 256 + threadIdx.x;
        int r = idx >> 5, cc = idx & 31;
        WT[(size_t)(bx + r) * 1024 + by + cc] = f2bf(t[cc][r]);
    }
}

// ---------------------------------------------------------------------------
// GEMM core v4: 256x256 tile, 8 waves, wave-tile 128x64, BK=32, 4 LDS bufs,
// 3-ahead prefetch with counted vmcnt, one barrier per K-step, frag ping-pong.
// ---------------------------------------------------------------------------
__device__ __forceinline__ void gemm_core256(const u16* A, const u16* BT,
                                             int m0, int n0, f32x4 acc[8][4]) {
    __shared__ __align__(16) short As[4][256 * 32];
    __shared__ __align__(16) short Bs[4][256 * 32];
    const int tid = threadIdx.x;
    const int lane = tid & 63, w = tid >> 6;
    const int wr = w >> 2, wc = w & 3;
    const int ln15 = lane & 15, kch = lane >> 4;
    const int erow = tid >> 2;
    const int ecol = (((tid & 3) ^ ((tid >> 3) & 3)) << 3);

#define STAGE256(buf, t)                                                      \
    {   const int k0_ = (t) * 32;                                             \
        _Pragma("unroll")                                                     \
        for (int rr = 0; rr < 2; ++rr) {                                      \
            gld_lds16(A  + (size_t)(m0 + rr * 128 + erow) * 1024 + k0_ + ecol,\
                      (short*)As[buf] + rr * 4096 + tid * 8);                 \
            gld_lds16(BT + (size_t)(n0 + rr * 128 + erow) * 1024 + k0_ + ecol,\
                      (short*)Bs[buf] + rr * 4096 + tid * 8);                 \
        } }

#define RF256(Fa, Fb, buf)                                                    \
    {   _Pragma("unroll")                                                     \
        for (int i = 0; i < 8; ++i) {                                         \
            int row = wr * 128 + i * 16 + ln15;                               \
            Fa[i] = *(const short8*)&As[buf][row * 32 + ((kch ^ ((row >> 1) & 3)) << 3)]; \
        }                                                                     \
        _Pragma("unroll")                                                     \
        for (int j = 0; j < 4; ++j) {                                         \
            int row = wc * 64 + j * 16 + ln15;                                \
            Fb[j] = *(const short8*)&Bs[buf][row * 32 + ((kch ^ ((row >> 1) & 3)) << 3)]; \
        } }

#define MM256(Fa, Fb)                                                         \
    {   __builtin_amdgcn_s_setprio(1);                                        \
        _Pragma("unroll")                                                     \
        for (int i = 0; i < 8; ++i)                                           \
            _Pragma("unroll")                                                 \
            for (int j = 0; j < 4; ++j)                                       \
                acc[i][j] = __builtin_amdgcn_mfma_f32_16x16x32_bf16(Fa[i], Fb[j], acc[i][j], 0, 0, 0); \
        __builtin_amdgcn_s_setprio(0); }

#define BODY256(t, Ca, Cb, Na, Nb)                                            \
    {   if ((t) + 3 < 32) STAGE256(((t) + 3) & 3, (t) + 3);                   \
        if ((t) < 29)       asm volatile("s_waitcnt vmcnt(8)" ::: "memory");  \
        else if ((t) == 29) asm volatile("s_waitcnt vmcnt(4)" ::: "memory");  \
        else if ((t) == 30) asm volatile("s_waitcnt vmcnt(0)" ::: "memory");  \
        asm volatile("s_waitcnt lgkmcnt(0)" ::: "memory");                    \
        __builtin_amdgcn_s_barrier();                                         \
        if ((t) < 31) RF256(Na, Nb, ((t) + 1) & 3);                           \
        MM256(Ca, Cb); }

    short8 Xa[8], Xb[4], Ya[8], Yb[4];
    STAGE256(0, 0);
    STAGE256(1, 1);
    STAGE256(2, 2);
    asm volatile("s_waitcnt vmcnt(8)" ::: "memory");
    __builtin_amdgcn_s_barrier();
    RF256(Xa, Xb, 0);
    for (int t2 = 0; t2 < 32; t2 += 2) {
        BODY256(t2, Xa, Xb, Ya, Yb);
        BODY256(t2 + 1, Ya, Yb, Xa, Xb);
    }
#undef STAGE256
#undef RF256
#undef MM256
#undef BODY256
}

// ---------------------------------------------------------------------------
// GEMM core 128x256: A-tile 128x32 (1 load/thr), B-tile 256x32 (2 loads/thr),
// 8 waves wave-tile 64x64, 4 LDS bufs (96KB), counted vmcnt(6)/(3)/(0).
// For the final GEMM: 256 blocks = exactly 1/CU (full-chip makespan).
// ---------------------------------------------------------------------------
__device__ __forceinline__ void gemm_core128(const u16* A, const u16* BT,
                                             int m0, int n0, f32x4 acc[4][4]) {
    __shared__ __align__(16) short As[4][128 * 32];
    __shared__ __align__(16) short Bs[4][256 * 32];
    const int tid = threadIdx.x;
    const int lane = tid & 63, w = tid >> 6;
    const int wr = w >> 2, wc = w & 3;          // 2 x 4 waves
    const int ln15 = lane & 15, kch = lane >> 4;
    const int erow = tid >> 2;                   // 0..127
    const int ecol = (((tid & 3) ^ ((tid >> 3) & 3)) << 3);

#define STAGE128(buf, t)                                                      \
    {   const int k0_ = (t) * 32;                                             \
        gld_lds16(A + (size_t)(m0 + erow) * 1024 + k0_ + ecol,                \
                  (short*)As[buf] + tid * 8);                                 \
        _Pragma("unroll")                                                     \
        for (int rr = 0; rr < 2; ++rr) {                                      \
            gld_lds16(BT + (size_t)(n0 + rr * 128 + erow) * 1024 + k0_ + ecol,\
                      (short*)Bs[buf] + rr * 4096 + tid * 8);                 \
        } }

#define RF128(Fa, Fb, buf)                                                    \
    {   _Pragma("unroll")                                                     \
        for (int i = 0; i < 4; ++i) {                                         \
            int row = wr * 64 + i * 16 + ln15;                                \
            Fa[i] = *(const short8*)&As[buf][row * 32 + ((kch ^ ((row >> 1) & 3)) << 3)]; \
        }                                                                     \
        _Pragma("unroll")                                                     \
        for (int j = 0; j < 4; ++j) {                                         \
            int row = wc * 64 + j * 16 + ln15;                                \
            Fb[j] = *(const short8*)&Bs[buf][row * 32 + ((kch ^ ((row >> 1) & 3)) << 3)]; \
        } }

#define MM128(Fa, Fb)                                                         \
    {   __builtin_amdgcn_s_setprio(1);                                        \
        _Pragma("unroll")                                                     \
        for (int i = 0; i < 4; ++i)                                           \
            _Pragma("unroll")                                                 \
            for (int j = 0; j < 4; ++j)                                       \
                acc[i][j] = __builtin_amdgcn_mfma_f32_16x16x32_bf16(Fa[i], Fb[j], acc[i][j], 0, 0, 0); \
        __builtin_amdgcn_s_setprio(0); }

#define BODY128(t, Ca, Cb, Na, Nb)                                            \
    {   if ((t) + 3 < 32) STAGE128(((t) + 3) & 3, (t) + 3);                   \
        if ((t) < 29)       asm volatile("s_waitcnt vmcnt(6)" ::: "memory");  \
        else if ((t) == 29) asm volatile("s_waitcnt vmcnt(3)" ::: "memory");  \
        else if ((t) == 30) asm volatile("s_waitcnt vmcnt(0)" ::: "memory");  \
        asm volatile("s_waitcnt lgkmcnt(0)" ::: "memory");                    \
        __builtin_amdgcn_s_barrier();                                         \
        if ((t) < 31) RF128(Na, Nb, ((t) + 1) & 3);                           \
        MM128(Ca, Cb); }

    short8 Xa[4], Xb[4], Ya[4], Yb[4];
    STAGE128(0, 0);
    STAGE128(1, 1);
    STAGE128(2, 2);
    asm volatile("s_waitcnt vmcnt(6)" ::: "memory");
    __builtin_amdgcn_s_barrier();
    RF128(Xa, Xb, 0);
    for (int t2 = 0; t2 < 32; t2 += 2) {
        BODY128(t2, Xa, Xb, Ya, Yb);
        BODY128(t2 + 1, Ya, Yb, Xa, Xb);
    }
#undef STAGE128
#undef RF128
#undef MM128
#undef BODY128
}

// XCD-bijective swizzle (nwg % 8 == 0)
__device__ __forceinline__ int xcd_swz(int lid, int nwg) {
    int q = nwg >> 3;
    return (lid & 7) * q + (lid >> 3);
}

// final GEMM: 128x256 tiles -> grid (4, 64) = 256 blocks = 1/CU
__global__ __launch_bounds__(512, 2) void gemm_bf16(const u16* __restrict__ A,
                                                    const u16* __restrict__ BT,
                                                    float* __restrict__ C) {
    const int lid = blockIdx.y * 4 + blockIdx.x;
    const int sid = xcd_swz(lid, 256);
    const int m0 = (sid >> 2) * 128, n0 = (sid & 3) * 256;
    f32x4 acc[4][4] = {};
    gemm_core128(A, BT, m0, n0, acc);
    const int lane = threadIdx.x & 63, w = threadIdx.x >> 6;
    const int crow0 = m0 + (w >> 2) * 64 + (lane >> 4) * 4;
    const int ccol0 = n0 + (w & 3) * 64 + (lane & 15);
#pragma unroll
    for (int i = 0; i < 4; ++i)
#pragma unroll
        for (int j = 0; j < 4; ++j)
#pragma unroll
            for (int r = 0; r < 4; ++r)
                C[(size_t)(crow0 + i * 16 + r) * 1024 + ccol0 + j * 16] = acc[i][j][r];
}

__global__ __launch_bounds__(512, 2) void gemm_qkv(const u16* __restrict__ A,
                                                   const u16* __restrict__ WT0,
                                                   u16* __restrict__ xq16,
                                                   u16* __restrict__ xk16,
                                                   u16* __restrict__ xv16) {
    const int lid = blockIdx.y * 12 + blockIdx.x;
    const int sid = xcd_swz(lid, 384);
    const int lbx = sid % 12;
    const int which = lbx >> 2;
    const int n0 = (lbx & 3) * 256;
    const int m0 = (sid / 12) * 256;
    const u16* BT = WT0 + (size_t)which * 1048576;
    f32x4 acc[8][4] = {};
    gemm_core256(A, BT, m0, n0, acc);
    const int lane = threadIdx.x & 63, w = threadIdx.x >> 6;
    const int crow0 = m0 + (w >> 2) * 128 + (lane >> 4) * 4;
    const int ccol0 = n0 + (w & 3) * 64 + (lane & 15);
    u16* C16 = (which == 0) ? xq16 : (which == 1) ? xk16 : xv16;
#pragma unroll
    for (int i = 0; i < 8; ++i)
#pragma unroll
        for (int j = 0; j < 4; ++j)
#pragma unroll
            for (int r = 0; r < 4; ++r)
                C16[(size_t)(crow0 + i * 16 + r) * 1024 + ccol0 + j * 16] = f2bf(acc[i][j][r]);
}

// ---------------------------------------------------------------------------
// beta = sigmoid(x @ Wb) stored [B,H,L]; reads bf16 x
// ---------------------------------------------------------------------------
__global__ __launch_bounds__(256) void beta_k(const u16* __restrict__ X16,
                                              const float* __restrict__ Wb,
                                              float* __restrict__ beta) {
    int idx = blockIdx.x * 256 + threadIdx.x;
    int row = idx >> 4, h = idx & 15;
    const u16* xr = X16 + (size_t)row * DD;
    float s = 0.f;
    for (int k8 = 0; k8 < DD; k8 += 8) {
        short8 xv = *(const short8*)&xr[k8];
#pragma unroll
        for (int e = 0; e < 8; ++e)
            s += bf2f((u16)xv[e]) * Wb[(k8 + e) * HH + h];
    }
    float bv = 1.f / (1.f + expf(-s));
    int b = row >> 12, l = row & (LL - 1);
    beta[((size_t)b * HH + h) * LL + l] = bv;
}

// ---------------------------------------------------------------------------
// 3x fused conv, all bf16: which 0=q(norm) 1=k(norm) 2=v
// ---------------------------------------------------------------------------
__global__ __launch_bounds__(256) void conv3_k(const u16* __restrict__ xq16,
                                               const u16* __restrict__ xk16,
                                               const u16* __restrict__ xv16,
                                               const float* __restrict__ cwq,
                                               const float* __restrict__ cwk,
                                               const float* __restrict__ cwv,
                                               u16* __restrict__ q16,
                                               u16* __restrict__ k16,
                                               u16* __restrict__ v16) {
    const int which = blockIdx.z;
    const float* cw = (which == 0) ? cwq : (which == 1) ? cwk : cwv;
    const int l0 = blockIdx.x * 16, b = blockIdx.y;
    const int tid = threadIdx.x;
    const int d0 = tid * 4;
    const float4 w0 = *(const float4*)&cw[(d0 + 0) * 4];
    const float4 w1 = *(const float4*)&cw[(d0 + 1) * 4];
    const float4 w2 = *(const float4*)&cw[(d0 + 2) * 4];
    const float4 w3 = *(const float4*)&cw[(d0 + 3) * 4];
    const int h = d0 >> 6, hd = d0 & 63;
    const u16* Xb = ((which == 0) ? xq16 : (which == 1) ? xk16 : xv16) + (size_t)b * LL * DD;
    u16* O16 = (which == 0) ? q16 : (which == 1) ? k16 : v16;
    float4 xm3 = make_float4(0, 0, 0, 0), xm2 = xm3, xm1 = xm3;
    if (l0 > 0) {
        xm3 = ld_bf4(&Xb[(size_t)(l0 - 3) * DD + d0]);
        xm2 = ld_bf4(&Xb[(size_t)(l0 - 2) * DD + d0]);
        xm1 = ld_bf4(&Xb[(size_t)(l0 - 1) * DD + d0]);
    }
#pragma unroll
    for (int t = 0; t < 16; ++t) {
        const int l = l0 + t;
        float4 xc = ld_bf4(&Xb[(size_t)l * DD + d0]);
        float a0 = xm3.x * w0.x + xm2.x * w0.y + xm1.x * w0.z + xc.x * w0.w;
        float a1 = xm3.y * w1.x + xm2.y * w1.y + xm1.y * w1.z + xc.y * w1.w;
        float a2 = xm3.z * w2.x + xm2.z * w2.y + xm1.z * w2.z + xc.z * w2.w;
        float a3 = xm3.w * w3.x + xm2.w * w3.y + xm1.w * w3.z + xc.w * w3.w;
        a0 = a0 / (1.f + expf(-a0));
        a1 = a1 / (1.f + expf(-a1));
        a2 = a2 / (1.f + expf(-a2));
        a3 = a3 / (1.f + expf(-a3));
        if (which < 2) {
            float s = a0 * a0 + a1 * a1 + a2 * a2 + a3 * a3;
            s += __shfl_xor(s, 1);
            s += __shfl_xor(s, 2);
            s += __shfl_xor(s, 4);
            s += __shfl_xor(s, 8);
            float sc = rsqrtf(s);
            a0 *= sc; a1 *= sc; a2 *= sc; a3 *= sc;
        }
        uint2 o;
        o.x = (unsigned)f2bf(a0) | ((unsigned)f2bf(a1) << 16);
        o.y = (unsigned)f2bf(a2) | ((unsigned)f2bf(a3) << 16);
        *(uint2*)&O16[(((size_t)b * HH + h) * LL + l) * 64 + hd] = o;
        xm3 = xm2; xm2 = xm1; xm1 = xc;
    }
}

// ---------------------------------------------------------------------------
// Phase A: K,V exact bf16. W,U plain bf16 out. P,B plain fp32 out.
// ---------------------------------------------------------------------------
__global__ __launch_bounds__(256) void phaseA6(const u16* __restrict__ kg16,
                                               const u16* __restrict__ vg16,
                                               const float* __restrict__ betag,
                                               u16* __restrict__ Wg16,
                                               u16* __restrict__ UgT16,
                                               float* __restrict__ Pall,
                                               float* __restrict__ BallT) {
    __shared__ __align__(16) char pool[65536];
    u16* Kh   = (u16*)pool;              // 0-8K; later WTh
    u16* KTh  = (u16*)(pool + 8192);     // 8-16K (persists)
    float* At = (float*)(pool + 16384);  // 16-32K; later WTl/UTh
    float* WU = (float*)(pool + 32768);  // 32-64K; later scr/scrP
    u16* WTh  = (u16*)pool;
    u16* WTl  = (u16*)(pool + 16384);
    u16* UTh  = (u16*)(pool + 24576);
    float* scr  = (float*)(pool + 32768);  // B scratch (32-48K)
    float* scrP = (float*)(pool + 49152);  // P scratch (48-64K)

    const int c = blockIdx.x, bh = blockIdx.y;
    const int tid = threadIdx.x, lane = tid & 63, w = tid >> 6;
    const int g = lane >> 4, ln = lane & 15;
    const int t0 = (tid >> 4) * 4, d4 = (tid & 15) * 4;
    const size_t base = ((size_t)bh * LL + (size_t)c * 64) * 64;
    const size_t obase = ((size_t)bh * NC + c) * 4096;
    const float* bet = betag + (size_t)bh * LL + (size_t)c * 64;

    // 1a. K (bf16) -> Kh swizzled
    g_to_ls_b(kg16 + base, Kh, tid);
    // 1b. K^T -> KTh (global re-read 4x4, packed transposed stores)
    {
        u16 kv[4][4];
#pragma unroll
        for (int i = 0; i < 4; ++i) {
            uint2 v = *(const uint2*)&kg16[base + (size_t)(t0 + i) * 64 + d4];
            kv[i][0] = (u16)v.x; kv[i][1] = (u16)(v.x >> 16);
            kv[i][2] = (u16)v.y; kv[i][3] = (u16)(v.y >> 16);
        }
#pragma unroll
        for (int j = 0; j < 4; ++j) {
            uint2 hv;
            hv.x = (unsigned)kv[0][j] | ((unsigned)kv[1][j] << 16);
            hv.y = (unsigned)kv[2][j] | ((unsigned)kv[3][j] << 16);
            *(uint2*)&KTh[swze(d4 + j, t0)] = hv;
        }
    }
    __syncthreads();
    // 2. Gram A = strict_tril(beta * K K^T)
    {
        f32x4 acc[4] = {};
        mm64_bb(Kh, Kh, acc, w, lane);
#pragma unroll
        for (int r = 0; r < 4; ++r) {
            int t = w * 16 + g * 4 + r;
            float bt = bet[t];
#pragma unroll
            for (int j = 0; j < 4; ++j) {
                int s = j * 16 + ln;
                At[t * 64 + s] = (s < t) ? bt * acc[j][r] : 0.f;
            }
        }
    }
    // 3. RHS: WU[t][j] = beta_t * (j<64 ? K[t][j] : V[t][j-64])
#pragma unroll
    for (int p = 0; p < 8; ++p) {
        int flat = p * 1024 + tid * 4;
        int t = flat >> 7, j = flat & 127;
        float bt = bet[t];
        float4 src;
        if (j < 64) src = ld_bf4(&Kh[swze(t, j)]);
        else        src = ld_bf4(&vg16[base + (size_t)t * 64 + (j - 64)]);
        src.x *= bt; src.y *= bt; src.z *= bt; src.w *= bt;
        *(float4*)&WU[t * 128 + j] = src;
    }
    __syncthreads();
    // 4. blocked forward substitution (panels of 16)
#pragma unroll
    for (int pb = 0; pb < 4; ++pb) {
        const int r0 = pb * 16;
        if (pb > 0) {
            const int col = tid & 127;
            const int rbase = r0 + (tid >> 7) * 8;
            float acc8[8] = {};
            for (int r = 0; r < r0; r += 4) {
                float u0 = WU[(r + 0) * 128 + col], u1 = WU[(r + 1) * 128 + col];
                float u2 = WU[(r + 2) * 128 + col], u3 = WU[(r + 3) * 128 + col];
#pragma unroll
                for (int i = 0; i < 8; ++i) {
                    float4 a4 = *(const float4*)&At[(rbase + i) * 64 + r];
                    acc8[i] += a4.x * u0 + a4.y * u1 + a4.z * u2 + a4.w * u3;
                }
            }
#pragma unroll
            for (int i = 0; i < 8; ++i) WU[(rbase + i) * 128 + col] -= acc8[i];
            __syncthreads();
        }
        if (tid < 128) {
            const int col = tid;
            float wv[16];
            wv[0] = WU[r0 * 128 + col];
#pragma unroll
            for (int t = 1; t < 16; ++t) {
                float a = WU[(r0 + t) * 128 + col];
#pragma unroll
                for (int r = 0; r < t; ++r) a -= At[(r0 + t) * 64 + r0 + r] * wv[r];
                wv[t] = a;
            }
#pragma unroll
            for (int t = 1; t < 16; ++t) WU[(r0 + t) * 128 + col] = wv[t];
        }
        __syncthreads();
    }
    // 5a. Wg16 global write (plain bf16, coalesced uint2)
#pragma unroll
    for (int p = 0; p < 4; ++p) {
        int flat = p * 1024 + tid * 4;
        int t = flat >> 6, j = flat & 63;
        float4 v = *(const float4*)&WU[t * 128 + j];
        uint2 o;
        o.x = (unsigned)f2bf(v.x) | ((unsigned)f2bf(v.y) << 16);
        o.y = (unsigned)f2bf(v.z) | ((unsigned)f2bf(v.w) << 16);
        *(uint2*)&Wg16[obase + flat] = o;
    }
    // 5b. W^T split build + U^T plain-bf16 build (transposed packed stores)
    {
        u16 h4[4][4], l4[4][4];
#pragma unroll
        for (int i = 0; i < 4; ++i) {
            float4 v = *(const float4*)&WU[(t0 + i) * 128 + d4];
            split2(v.x, h4[i][0], l4[i][0]); split2(v.y, h4[i][1], l4[i][1]);
            split2(v.z, h4[i][2], l4[i][2]); split2(v.w, h4[i][3], l4[i][3]);
        }
#pragma unroll
        for (int j = 0; j < 4; ++j) {
            uint2 hv, lv;
            hv.x = (unsigned)h4[0][j] | ((unsigned)h4[1][j] << 16);
            hv.y = (unsigned)h4[2][j] | ((unsigned)h4[3][j] << 16);
            lv.x = (unsigned)l4[0][j] | ((unsigned)l4[1][j] << 16);
            lv.y = (unsigned)l4[2][j] | ((unsigned)l4[3][j] << 16);
            *(uint2*)&WTh[swze(d4 + j, t0)] = hv;
            *(uint2*)&WTl[swze(d4 + j, t0)] = lv;
        }
#pragma unroll
        for (int i = 0; i < 4; ++i) {
            float4 v = *(const float4*)&WU[(t0 + i) * 128 + 64 + d4];
            h4[i][0] = f2bf(v.x); h4[i][1] = f2bf(v.y);
            h4[i][2] = f2bf(v.z); h4[i][3] = f2bf(v.w);
        }
#pragma unroll
        for (int j = 0; j < 4; ++j) {
            uint2 hv;
            hv.x = (unsigned)h4[0][j] | ((unsigned)h4[1][j] << 16);
            hv.y = (unsigned)h4[2][j] | ((unsigned)h4[3][j] << 16);
            *(uint2*)&UTh[swze(d4 + j, t0)] = hv;
        }
    }
    __syncthreads();
    // 6. UgT16 global write (plain bf16 from UTh, coalesced short8)
#pragma unroll
    for (int p = 0; p < 2; ++p) {
        int flat = p * 2048 + tid * 8;
        int n = flat >> 6, tt = flat & 63;
        *(short8*)&UgT16[obase + flat] = *(const short8*)&UTh[swze(n, tt)];
    }
    // 7. P = I - K^T W (split W); B = K^T U (U exact, 1-term)
    f32x4 aP[4] = {}, aB[4] = {};
    mm64_ab(KTh, WTh, WTl, aP, w, lane);
    mm64_bb(KTh, UTh, aB, w, lane);
#pragma unroll
    for (int j = 0; j < 4; ++j)
#pragma unroll
        for (int r = 0; r < 4; ++r) {
            int row = w * 16 + g * 4 + r, col = j * 16 + ln;
            scrP[swz(row, col)] = ((row == col) ? 1.f : 0.f) - aP[j][r];
            scr[swz(row, col)] = aB[j][r];
        }
    __syncthreads();
    // 8. Pall (plain) + BallT (transposed), both coalesced fp32 float4 streams
#pragma unroll
    for (int p = 0; p < 4; ++p) {
        int flat = p * 1024 + tid * 4;
        int rr = flat >> 6, cc = flat & 63;
        float4 op = make_float4(scrP[swz(rr, cc + 0)], scrP[swz(rr, cc + 1)],
                                scrP[swz(rr, cc + 2)], scrP[swz(rr, cc + 3)]);
        *(float4*)&Pall[obase + flat] = op;
        float4 ob4 = make_float4(scr[swz(cc + 0, rr)], scr[swz(cc + 1, rr)],
                                 scr[swz(cc + 2, rr)], scr[swz(cc + 3, rr)]);
        *(float4*)&BallT[obase + flat] = ob4;
    }
}

// ---------------------------------------------------------------------------
// compose4: fp32 I/O + T14 register prefetch of next P tile.
// ---------------------------------------------------------------------------
__global__ __launch_bounds__(256) void compose4(const float* __restrict__ Pall,
                                                const float* __restrict__ BallT,
                                                float* __restrict__ Pg,
                                                float* __restrict__ BgT) {
    __shared__ __align__(16) char pool[81920];
    u16* Ph = (u16*)pool;
    u16* Pl = (u16*)(pool + 8192);
    u16* Bh = (u16*)(pool + 16384);
    u16* Bl = (u16*)(pool + 24576);
    u16* nh = (u16*)(pool + 32768);
    u16* nl = (u16*)(pool + 40960);
    float* scr = (float*)(pool + 49152);
    const int g = blockIdx.x, bh = blockIdx.y;
    const int tid = threadIdx.x, lane = tid & 63, w = tid >> 6;
    const int gi = lane >> 4, ln = lane & 15;
    const size_t base0 = ((size_t)bh * NC + (size_t)g * GS) * 4096;
    f32x4 mP[4], mB[4];
#pragma unroll
    for (int p = 0; p < 4; ++p) {
        int flat = p * 1024 + tid * 4;
        int r = flat >> 6, c4 = flat & 63;
        *(float4*)&scr[swz(r, c4)] = *(const float4*)&Pall[base0 + flat];
    }
    g_to_frag(BallT + base0, mB, w, lane);
    __syncthreads();
#pragma unroll
    for (int j = 0; j < 4; ++j)
#pragma unroll
        for (int r = 0; r < 4; ++r) {
            int row = w * 16 + gi * 4 + r, col = j * 16 + ln;
            mP[j][r] = scr[swz(col, row)];
        }
    float4 pf[4];
    pload_f(pf, Pall + base0 + 4096, tid);
    for (int s = 1; s < GS; ++s) {
        __syncthreads();
        frag_to_ls(mP, Ph, Pl, w, lane);
        frag_to_ls(mB, Bh, Bl, w, lane);
        pstore_ls_f(pf, nh, nl, tid);
        __syncthreads();
        if (s < GS - 1) pload_f(pf, Pall + base0 + (size_t)(s + 1) * 4096, tid);
        f32x4 aP[4] = {}, aB[4] = {};
        mm64(Ph, Pl, nh, nl, aP, w, lane);
        mm64(Bh, Bl, nh, nl, aB, w, lane);
        g_add_frag(BallT + base0 + (size_t)s * 4096, aB, w, lane);
#pragma unroll
        for (int j = 0; j < 4; ++j) { mP[j] = aP[j]; mB[j] = aB[j]; }
    }
    const size_t gbase = ((size_t)bh * GG + g) * 4096;
    frag_to_g(mB, BgT + gbase, w, lane);
    __syncthreads();
#pragma unroll
    for (int j = 0; j < 4; ++j)
#pragma unroll
        for (int r = 0; r < 4; ++r) {
            int row = w * 16 + gi * 4 + r, col = j * 16 + ln;
            scr[swz(row, col)] = mP[j][r];
        }
    __syncthreads();
#pragma unroll
    for (int p = 0; p < 4; ++p) {
        int flat = p * 1024 + tid * 4;
        int a = flat >> 6, b0 = flat & 63;
        float4 o = make_float4(scr[swz(b0 + 0, a)], scr[swz(b0 + 1, a)],
                               scr[swz(b0 + 2, a)], scr[swz(b0 + 3, a)]);
        *(float4*)&Pg[gbase + flat] = o;
    }
}

// ---------------------------------------------------------------------------
// scanG4: fp32 I/O.
// ---------------------------------------------------------------------------
__global__ __launch_bounds__(256) void scanG4(const float* __restrict__ Pg,
                                              const float* __restrict__ BgT,
                                              float* __restrict__ SallT) {
    __shared__ __align__(16) char pool[32768];
    u16* Sh = (u16*)pool;
    u16* Sl = (u16*)(pool + 8192);
    u16* nh = (u16*)(pool + 16384);
    u16* nl = (u16*)(pool + 24576);
    const int bh = blockIdx.x;
    const int tid = threadIdx.x, lane = tid & 63, w = tid >> 6;
    f32x4 mS[4] = {};
    for (int g = 0; g < GG; ++g) {
        const size_t sbase = ((size_t)bh * NC + (size_t)g * GS) * 4096;
        frag_to_g(mS, SallT + sbase, w, lane);
        if (g == GG - 1) break;
        __syncthreads();
        frag_to_ls(mS, Sh, Sl, w, lane);
        g_to_ls(Pg + ((size_t)bh * GG + g) * 4096, nh, nl, tid);
        __syncthreads();
        f32x4 a[4] = {};
        mm64(Sh, Sl, nh, nl, a, w, lane);
        g_add_frag(BgT + ((size_t)bh * GG + g) * 4096, a, w, lane);
#pragma unroll
        for (int j = 0; j < 4; ++j) mS[j] = a[j];
    }
}

// ---------------------------------------------------------------------------
// rollout4: fp32 I/O + T14 register prefetch.
// ---------------------------------------------------------------------------
__global__ __launch_bounds__(256) void rollout4(const float* __restrict__ Pall,
                                                const float* __restrict__ BallT,
                                                float* __restrict__ SallT) {
    __shared__ __align__(16) char pool[32768];
    u16* Sh = (u16*)pool;
    u16* Sl = (u16*)(pool + 8192);
    u16* nh = (u16*)(pool + 16384);
    u16* nl = (u16*)(pool + 24576);
    const int g = blockIdx.x, bh = blockIdx.y;
    const int tid = threadIdx.x, lane = tid & 63, w = tid >> 6;
    const size_t base0 = ((size_t)bh * NC + (size_t)g * GS) * 4096;
    f32x4 mS[4];
    g_to_frag(SallT + base0, mS, w, lane);
    float4 pf[4];
    pload_f(pf, Pall + base0, tid);
    for (int j = 1; j < GS; ++j) {
        __syncthreads();
        frag_to_ls(mS, Sh, Sl, w, lane);
        pstore_ls_f(pf, nh, nl, tid);
        __syncthreads();
        if (j < GS - 1) pload_f(pf, Pall + base0 + (size_t)j * 4096, tid);
        f32x4 a[4] = {};
        mm64(Sh, Sl, nh, nl, a, w, lane);
        g_add_frag(BallT + base0 + (size_t)(j - 1) * 4096, a, w, lane);
#pragma unroll
        for (int jj = 0; jj < 4; ++jj) mS[jj] = a[jj];
        frag_to_g(mS, SallT + base0 + (size_t)j * 4096, w, lane);
    }
}

// ---------------------------------------------------------------------------
// phaseO6: W,U plain bf16 (U staged to LDS); S fp32; Q,K exact bf16.
// M=causal(QK^T); Delta^T = U^T - (WS)^T; O = QS + M*Delta; fused RMSNorm.
// ---------------------------------------------------------------------------
__global__ __launch_bounds__(256) void phaseO6(const u16* __restrict__ Wg16,
                                               const u16* __restrict__ UgT16,
                                               const u16* __restrict__ qg16,
                                               const u16* __restrict__ kg16,
                                               const float* __restrict__ SallT,
                                               const float* __restrict__ nw,
                                               u16* __restrict__ ob) {
    __shared__ __align__(16) char pool[65536];
    u16* Qh = (u16*)pool;               // 8K
    u16* Kh = (u16*)(pool + 8192);      // 8K; later Dh
    u16* Wh = (u16*)(pool + 16384);     // 8K; later Mh
    u16* Wl = (u16*)(pool + 24576);     // 8K; Ml
    u16* Sh = (u16*)(pool + 32768);
    u16* Sl = (u16*)(pool + 40960);
    u16* Dl = (u16*)(pool + 49152);     // 8K
    u16* Uh = (u16*)(pool + 57344);     // 8K staged U^T
    u16* Dh = Kh;
    u16* Mh = Wh; u16* Ml = Wl;
    const int c = blockIdx.x, bh = blockIdx.y;
    const int b = bh >> 4, h = bh & 15;
    const int tid = threadIdx.x, lane = tid & 63, w = tid >> 6;
    const int gi = lane >> 4, ln = lane & 15;
    const size_t tbase = ((size_t)bh * NC + c) * 4096;
    const size_t qkbase = ((size_t)bh * LL + (size_t)c * 64) * 64;
    g_to_ls_b(qg16 + qkbase, Qh, tid);
    g_to_ls_b(kg16 + qkbase, Kh, tid);
    g_to_ls_b(Wg16 + tbase, Wh, tid);
    g_to_ls_b(UgT16 + tbase, Uh, tid);
    g_to_ls(SallT + tbase, Sh, Sl, tid);
    __syncthreads();
    f32x4 aM[4] = {}, aD[4] = {};
    mm64_bb(Qh, Kh, aM, w, lane);        // Q K^T
    mm64_sb(Sh, Sl, Wh, aD, w, lane);    // (W S)^T   (S split, W exact)
    __syncthreads();                     // all K/W reads done
#pragma unroll
    for (int j = 0; j < 4; ++j)
#pragma unroll
        for (int r = 0; r < 4; ++r) {
            int row = w * 16 + gi * 4 + r, col = j * 16 + ln;
            float mv = (col <= row) ? aM[j][r] : 0.f;
            u16 mh_, ml_; split2(mv, mh_, ml_);
            Mh[swze(row, col)] = mh_;
            Ml[swze(row, col)] = ml_;
            float dv = bf2f(Uh[swze(row, col)]) - aD[j][r];
            u16 dh_, dl_; split2(dv, dh_, dl_);
            Dh[swze(row, col)] = dh_;
            Dl[swze(row, col)] = dl_;
        }
    __syncthreads();
    f32x4 aO[4] = {};
    mm64_ab(Qh, Sh, Sl, aO, w, lane);    // Q S
    mm64(Mh, Ml, Dh, Dl, aO, w, lane);   // + M Delta
    float nwv[4];
#pragma unroll
    for (int j = 0; j < 4; ++j) nwv[j] = nw[j * 16 + ln];
#pragma unroll
    for (int r = 0; r < 4; ++r) {
        float ss = 0.f;
#pragma unroll
        for (int j = 0; j < 4; ++j) ss += aO[j][r] * aO[j][r];
        ss += __shfl_xor(ss, 1);
        ss += __shfl_xor(ss, 2);
        ss += __shfl_xor(ss, 4);
        ss += __shfl_xor(ss, 8);
        float rms = rsqrtf(ss * (1.f / 64.f) + 1e-5f);
        int row = w * 16 + gi * 4 + r;
        size_t orow = ((size_t)b * LL + (size_t)c * 64 + row) * DD + (size_t)h * 64;
#pragma unroll
        for (int j = 0; j < 4; ++j)
            ob[orow + j * 16 + ln] = f2bf(aO[j][r] * rms * nwv[j]);
    }
}

// ---------------------------------------------------------------------------
extern "C" void kernel_launch(void* const* d_in, const int* in_sizes, int n_in,
                              void* d_out, int out_size, void* d_ws, size_t ws_size,
                              hipStream_t stream) {
    const float* x  = (const float*)d_in[0];
    const float* Wq = (const float*)d_in[1];
    const float* Wk = (const float*)d_in[2];
    const float* Wv = (const float*)d_in[3];
    const float* Wb = (const float*)d_in[4];
    const float* cq = (const float*)d_in[5];
    const float* ck = (const float*)d_in[6];
    const float* cv = (const float*)d_in[7];
    const float* nw = (const float*)d_in[8];
    const float* Wo = (const float*)d_in[9];
    float* out = (float*)d_out;
    float* ws = (float*)d_ws;

    const size_t SZ = (size_t)BB * LL * DD;   // 8388608
    u16* xv16    = (u16*)ws;        // gemm v out; slab reused as Pall
    u16* v16     = (u16*)(ws + SZ); // conv v out; slab reused as ob
    u16* Wg16    = (u16*)(ws + 2 * SZ);       // plain bf16 W tiles
    u16* UgT16   = (u16*)(ws + 2 * SZ) + SZ;  // plain bf16 U^T tiles
    float* SallT = ws + 4 * SZ;
    u16* xb   = (u16*)(ws + 5 * SZ);          // x bf16; dead after conv/beta
    u16* q16  = xb;                           // conv q out (reuses xb)
    u16* xq16 = (u16*)(ws + 5 * SZ) + SZ;
    u16* xk16 = (u16*)(ws + 5 * SZ) + 2 * SZ;
    u16* k16  = (u16*)(ws + 5 * SZ) + 3 * SZ;
    float* beta = ws + 7 * SZ;                        // 131072 floats
    u16* wqT  = (u16*)(beta + (size_t)BH * LL);       // 4M u16 (q,k,v,o)
    float* Pg  = (float*)(wqT + (size_t)4 * 1048576); // 1M floats
    float* BgT = Pg + 1048576;                        // 1M floats

    float* Pall  = ws;        // overwrites xv16 (dead after conv3)
    float* BallT = out;       // d_out as scratch; fully overwritten by final GEMM
    u16* ob   = (u16*)(ws + SZ);   // overwrites v16 (dead after phaseA6)
    u16* woT  = wqT + (size_t)3 * 1048576;

    dim3 blk(256);

    prep_k<<<dim3(8192), blk, 0, stream>>>(x, xb, Wq, Wk, Wv, Wo, wqT);
    gemm_qkv<<<dim3(12, 32), dim3(512), 0, stream>>>(xb, wqT, xq16, xk16, xv16);
    beta_k<<<dim3(512), blk, 0, stream>>>(xb, Wb, beta);
    conv3_k<<<dim3(LL / 16, BB, 3), blk, 0, stream>>>(xq16, xk16, xv16, cq, ck, cv, q16, k16, v16);
    phaseA6<<<dim3(NC, BH), blk, 0, stream>>>(k16, v16, beta, Wg16, UgT16, Pall, BallT);
    compose4<<<dim3(GG, BH), blk, 0, stream>>>(Pall, BallT, Pg, BgT);
    scanG4<<<dim3(BH), blk, 0, stream>>>(Pg, BgT, SallT);
    rollout4<<<dim3(GG, BH), blk, 0, stream>>>(Pall, BallT, SallT);
    phaseO6<<<dim3(NC, BH), blk, 0, stream>>>(Wg16, UgT16, q16, k16, SallT, nw, ob);
    gemm_bf16<<<dim3(4, 64), dim3(512), 0, stream>>>(ob, woT, out);
}